// Round 8
// baseline (313.163 us; speedup 1.0000x reference)
//
#include <hip/hip_runtime.h>
#include <math.h>

#define C_IN 16
#define NTH 256
#define MTH 64   // MLP block size (1 wave)

// ---------------- degree count (int) ----------------
__global__ __launch_bounds__(NTH) void count_kernel(const int* __restrict__ dst, int E,
                                                    int* __restrict__ cnt) {
    int e = blockIdx.x * NTH + threadIdx.x;
    if (e < E) atomicAdd(&cnt[dst[e]], 1);
}

// ---------------- scan pass 1 + dinv/invdeg + xs1 prescale (fused; node domain) --------
__global__ __launch_bounds__(NTH) void scan1_kernel(const int* __restrict__ cnt, int n,
                                                    int* __restrict__ bsum,
                                                    float* __restrict__ dinv,
                                                    float* __restrict__ invdeg,
                                                    const float* __restrict__ x,
                                                    float* __restrict__ xs) {
    __shared__ int s[NTH];
    int i = blockIdx.x * NTH + threadIdx.x;
    int c = (i < n) ? cnt[i] : 0;
    if (i < n) {
        float d = (float)c + 1.0f;
        float di = rsqrtf(d);
        dinv[i] = di;
        invdeg[i] = 1.0f / d;
        const float4* xv = reinterpret_cast<const float4*>(x + (size_t)i * C_IN);
        float4* xsv = reinterpret_cast<float4*>(xs + (size_t)i * C_IN);
        #pragma unroll
        for (int c4 = 0; c4 < C_IN / 4; ++c4) {
            float4 v = xv[c4];
            v.x *= di; v.y *= di; v.z *= di; v.w *= di;
            xsv[c4] = v;
        }
    }
    s[threadIdx.x] = c;
    __syncthreads();
    for (int off = NTH / 2; off > 0; off >>= 1) {
        if (threadIdx.x < off) s[threadIdx.x] += s[threadIdx.x + off];
        __syncthreads();
    }
    if (threadIdx.x == 0) bsum[blockIdx.x] = s[0];
}

__global__ __launch_bounds__(NTH) void scan2_kernel(int* __restrict__ bsum, int nb) {
    __shared__ int s[NTH];
    int base = 0;
    for (int c = 0; c < nb; c += NTH) {
        int idx = c + threadIdx.x;
        int v = (idx < nb) ? bsum[idx] : 0;
        s[threadIdx.x] = v;
        __syncthreads();
        for (int off = 1; off < NTH; off <<= 1) {
            int x = (threadIdx.x >= off) ? s[threadIdx.x - off] : 0;
            __syncthreads();
            s[threadIdx.x] += x;
            __syncthreads();
        }
        if (idx < nb) bsum[idx] = base + s[threadIdx.x] - v;  // exclusive
        int tot = s[NTH - 1];
        __syncthreads();
        base += tot;
    }
}

__global__ __launch_bounds__(NTH) void scan3_kernel(const int* __restrict__ cnt,
                                                    const int* __restrict__ bsum, int n,
                                                    int* __restrict__ row,
                                                    int* __restrict__ cur) {
    __shared__ int s[NTH];
    int i = blockIdx.x * NTH + threadIdx.x;
    int v = (i < n) ? cnt[i] : 0;
    s[threadIdx.x] = v;
    __syncthreads();
    for (int off = 1; off < NTH; off <<= 1) {
        int x = (threadIdx.x >= off) ? s[threadIdx.x - off] : 0;
        __syncthreads();
        s[threadIdx.x] += x;
        __syncthreads();
    }
    if (i < n) {
        int excl = bsum[blockIdx.x] + s[threadIdx.x] - v;
        row[i] = excl;
        cur[i] = excl;
        if (i == n - 1) row[n] = excl + v;
    }
}

__global__ __launch_bounds__(NTH) void fill_kernel(const int* __restrict__ src,
                                                   const int* __restrict__ dst, int E,
                                                   int* __restrict__ cur,
                                                   int* __restrict__ csr) {
    int e = blockIdx.x * NTH + threadIdx.x;
    if (e < E) {
        int p = atomicAdd(&cur[dst[e]], 1);
        csr[p] = src[e];
    }
}

// ---------------- CSR gather: out[i] = dinv[i]*sum xs[src] + invdeg[i]*self[i] (+b, relu) --
template<int C, bool FINAL>
__global__ __launch_bounds__(NTH) void gather_kernel(const int* __restrict__ row,
                                                     const int* __restrict__ csr,
                                                     const float* __restrict__ xs,
                                                     const float* __restrict__ self,
                                                     const float* __restrict__ dinv,
                                                     const float* __restrict__ invdeg,
                                                     const float* __restrict__ bias,
                                                     float* __restrict__ out, int n) {
    constexpr int G = C / 4;                    // threads per node
    int i = blockIdx.x * (NTH / G) + threadIdx.x / G;
    int q = threadIdx.x % G;
    if (i >= n) return;
    int r0 = row[i], r1 = row[i + 1];
    float4 acc = make_float4(0.f, 0.f, 0.f, 0.f);
    int e = r0;
    // 8-wide unroll: 8 independent random loads in flight (L2/LLC latency-bound)
    for (; e + 7 < r1; e += 8) {
        int s0 = csr[e], s1 = csr[e+1], s2 = csr[e+2], s3 = csr[e+3];
        int s4 = csr[e+4], s5 = csr[e+5], s6 = csr[e+6], s7 = csr[e+7];
        float4 v0 = *reinterpret_cast<const float4*>(xs + (size_t)s0 * C + q * 4);
        float4 v1 = *reinterpret_cast<const float4*>(xs + (size_t)s1 * C + q * 4);
        float4 v2 = *reinterpret_cast<const float4*>(xs + (size_t)s2 * C + q * 4);
        float4 v3 = *reinterpret_cast<const float4*>(xs + (size_t)s3 * C + q * 4);
        float4 v4 = *reinterpret_cast<const float4*>(xs + (size_t)s4 * C + q * 4);
        float4 v5 = *reinterpret_cast<const float4*>(xs + (size_t)s5 * C + q * 4);
        float4 v6 = *reinterpret_cast<const float4*>(xs + (size_t)s6 * C + q * 4);
        float4 v7 = *reinterpret_cast<const float4*>(xs + (size_t)s7 * C + q * 4);
        acc.x += ((v0.x + v1.x) + (v2.x + v3.x)) + ((v4.x + v5.x) + (v6.x + v7.x));
        acc.y += ((v0.y + v1.y) + (v2.y + v3.y)) + ((v4.y + v5.y) + (v6.y + v7.y));
        acc.z += ((v0.z + v1.z) + (v2.z + v3.z)) + ((v4.z + v5.z) + (v6.z + v7.z));
        acc.w += ((v0.w + v1.w) + (v2.w + v3.w)) + ((v4.w + v5.w) + (v6.w + v7.w));
    }
    for (; e + 3 < r1; e += 4) {
        int s0 = csr[e], s1 = csr[e+1], s2 = csr[e+2], s3 = csr[e+3];
        float4 v0 = *reinterpret_cast<const float4*>(xs + (size_t)s0 * C + q * 4);
        float4 v1 = *reinterpret_cast<const float4*>(xs + (size_t)s1 * C + q * 4);
        float4 v2 = *reinterpret_cast<const float4*>(xs + (size_t)s2 * C + q * 4);
        float4 v3 = *reinterpret_cast<const float4*>(xs + (size_t)s3 * C + q * 4);
        acc.x += (v0.x + v1.x) + (v2.x + v3.x);
        acc.y += (v0.y + v1.y) + (v2.y + v3.y);
        acc.z += (v0.z + v1.z) + (v2.z + v3.z);
        acc.w += (v0.w + v1.w) + (v2.w + v3.w);
    }
    for (; e < r1; ++e) {
        int s0 = csr[e];
        float4 v0 = *reinterpret_cast<const float4*>(xs + (size_t)s0 * C + q * 4);
        acc.x += v0.x; acc.y += v0.y; acc.z += v0.z; acc.w += v0.w;
    }
    float di = dinv[i], idg = invdeg[i];
    float4 sv = *reinterpret_cast<const float4*>(self + (size_t)i * C + q * 4);
    float4 o;
    o.x = fmaf(acc.x, di, sv.x * idg);
    o.y = fmaf(acc.y, di, sv.y * idg);
    o.z = fmaf(acc.z, di, sv.z * idg);
    o.w = fmaf(acc.w, di, sv.w * idg);
    if (FINAL) {
        const float4 b = *reinterpret_cast<const float4*>(bias + q * 4);
        o.x = fmaxf(o.x + b.x, 0.f);
        o.y = fmaxf(o.y + b.y, 0.f);
        o.z = fmaxf(o.z + b.z, 0.f);
        o.w = fmaxf(o.w + b.w, 0.f);
    }
    *reinterpret_cast<float4*>(out + (size_t)i * C + q * 4) = o;
}

// ---------------- dense transform: h = [relu](g @ W + b); optional hsc = h * dinv ------
template<int CIN, int COUT, bool BIASRELU, bool WSC>
__global__ __launch_bounds__(NTH) void transform_kernel(const float* __restrict__ g,
                                                        const float* __restrict__ W,
                                                        const float* __restrict__ b,
                                                        const float* __restrict__ dinv,
                                                        float* __restrict__ h,
                                                        float* __restrict__ hsc, int n) {
    __shared__ float Ws[CIN * COUT];
    __shared__ float bs[COUT];
    for (int idx = threadIdx.x; idx < CIN * COUT; idx += NTH) Ws[idx] = W[idx];
    if (BIASRELU && threadIdx.x < COUT) bs[threadIdx.x] = b[threadIdx.x];
    __syncthreads();

    int i = blockIdx.x * NTH + threadIdx.x;
    if (i >= n) return;

    float xr[CIN];
    const float4* xv = reinterpret_cast<const float4*>(g + (size_t)i * CIN);
    #pragma unroll
    for (int k4 = 0; k4 < CIN / 4; ++k4) {
        float4 v = xv[k4];
        xr[k4*4+0] = v.x; xr[k4*4+1] = v.y; xr[k4*4+2] = v.z; xr[k4*4+3] = v.w;
    }

    float di = WSC ? dinv[i] : 0.f;
    float4* hv = reinterpret_cast<float4*>(h + (size_t)i * COUT);
    float4* hscv = WSC ? reinterpret_cast<float4*>(hsc + (size_t)i * COUT) : nullptr;

    #pragma unroll 1
    for (int c4 = 0; c4 < COUT / 4; ++c4) {
        float a0 = 0.f, a1 = 0.f, a2 = 0.f, a3 = 0.f;
        #pragma unroll
        for (int k = 0; k < CIN; ++k) {
            const float4 w = *reinterpret_cast<const float4*>(&Ws[k * COUT + c4 * 4]);
            float xk = xr[k];
            a0 = fmaf(xk, w.x, a0);
            a1 = fmaf(xk, w.y, a1);
            a2 = fmaf(xk, w.z, a2);
            a3 = fmaf(xk, w.w, a3);
        }
        if (BIASRELU) {
            const float4 bv = *reinterpret_cast<const float4*>(&bs[c4 * 4]);
            a0 = fmaxf(a0 + bv.x, 0.f);
            a1 = fmaxf(a1 + bv.y, 0.f);
            a2 = fmaxf(a2 + bv.z, 0.f);
            a3 = fmaxf(a3 + bv.w, 0.f);
        }
        float4 o; o.x = a0; o.y = a1; o.z = a2; o.w = a3;
        hv[c4] = o;
        if (WSC) {
            float4 s; s.x = a0 * di; s.y = a1 * di; s.z = a2 * di; s.w = a3 * di;
            hscv[c4] = s;
        }
    }
}

// ---------------- MLP head: j-on-lanes, weights in VGPRs, ZERO LDS -----------------------
// R7 post-mortem: every LDS-broadcast variant hit the same ~65us wall -> LDS-pipe bound
// (compiler fissions the jj loop, re-reading Wl 4x). New dataflow: lane <-> hidden unit j,
// 64 Wf1 weights per lane in registers, node row h3[i,:] read via wave-uniform broadcast
// loads, per-node 6-step shuffle butterfly for the j-sum. No LDS reads at all.
// grid: (ceil(n/NODE_TILE), 8); each block covers j in [jb*128, jb*128+128).
__global__ __launch_bounds__(MTH, 2) void mlp_j_kernel(const float* __restrict__ h3,
                                                       const float* __restrict__ Wf1,
                                                       const float* __restrict__ bf1,
                                                       const float* __restrict__ Wf2,
                                                       float* __restrict__ part, int n) {
    constexpr int NODE_TILE = 128;
    const int lane = threadIdx.x;            // 0..63
    const int jb = blockIdx.y;               // 0..7
    const int j0 = jb * 128 + lane;
    const int j1 = j0 + 64;

    // per-lane weights: Wf1[k][j0], Wf1[k][j1], k=0..31 (coalesced across lanes)
    float w0[32], w1[32];
    #pragma unroll
    for (int k = 0; k < 32; ++k) {
        w0[k] = Wf1[k * 1024 + j0];
        w1[k] = Wf1[k * 1024 + j1];
    }
    const float b0 = bf1[j0], b1 = bf1[j1];
    const float g0 = Wf2[j0], g1 = Wf2[j1];

    const int ibeg = blockIdx.x * NODE_TILE;
    const int iend = min(ibeg + NODE_TILE, n);
    float* slice = part + (size_t)jb * n;

    #pragma unroll 2
    for (int i = ibeg; i < iend; ++i) {
        const float4* tv = reinterpret_cast<const float4*>(h3 + (size_t)i * 32);
        float z0 = b0, z1 = b1;
        #pragma unroll
        for (int k4 = 0; k4 < 8; ++k4) {
            const float4 t = tv[k4];         // uniform address across wave: broadcast load
            z0 = fmaf(t.x, w0[k4*4+0], z0); z1 = fmaf(t.x, w1[k4*4+0], z1);
            z0 = fmaf(t.y, w0[k4*4+1], z0); z1 = fmaf(t.y, w1[k4*4+1], z1);
            z0 = fmaf(t.z, w0[k4*4+2], z0); z1 = fmaf(t.z, w1[k4*4+2], z1);
            z0 = fmaf(t.w, w0[k4*4+3], z0); z1 = fmaf(t.w, w1[k4*4+3], z1);
        }
        float p = fmaf(fmaxf(z0, 0.f), g0, fmaxf(z1, 0.f) * g1);
        // 64-lane butterfly sum
        #pragma unroll
        for (int m = 1; m < 64; m <<= 1) p += __shfl_xor(p, m, 64);
        if (lane == 0) slice[i] = p;
    }
}

__global__ __launch_bounds__(NTH) void sigmoid_kernel(const float* __restrict__ part,
                                                      const float* __restrict__ bf2,
                                                      float* __restrict__ out, int n) {
    int i = blockIdx.x * NTH + threadIdx.x;
    if (i < n) {
        float z = bf2[0];
        #pragma unroll
        for (int s = 0; s < 8; ++s) z += part[(size_t)s * n + i];
        out[i] = 1.0f / (1.0f + expf(-z));
    }
}

extern "C" void kernel_launch(void* const* d_in, const int* in_sizes, int n_in,
                              void* d_out, int out_size, void* d_ws, size_t ws_size,
                              hipStream_t stream) {
    const float* x    = (const float*)d_in[0];
    const int*   ei   = (const int*)d_in[1];
    const float* W1   = (const float*)d_in[2];
    const float* b1   = (const float*)d_in[3];
    const float* W2   = (const float*)d_in[4];
    const float* b2   = (const float*)d_in[5];
    const float* W3   = (const float*)d_in[6];
    const float* b3   = (const float*)d_in[7];
    const float* Wf1  = (const float*)d_in[8];
    const float* bf1  = (const float*)d_in[9];
    const float* Wf2  = (const float*)d_in[10];
    const float* bf2  = (const float*)d_in[11];
    float* out = (float*)d_out;

    const int n = in_sizes[0] / C_IN;          // 50000
    const int E = in_sizes[1] / 2;             // 800000
    const int* src = ei;
    const int* dst = ei + E;

    // ---- workspace layout ----
    float* ws = (float*)d_ws;
    float* dinv   = ws;                          // [n]
    float* invdeg = ws + (size_t)n;              // [n]
    float* part   = ws + (size_t)2 * n;          // [8n]
    float* buf1   = ws + (size_t)18 * n;         // [64n]
    float* buf2   = ws + (size_t)82 * n;         // [64n]
    float* buf3   = ws + (size_t)146 * n;        // [32n]
    int*   iw     = (int*)(ws + (size_t)178 * n);
    int*   cnt    = iw;                          // [n]
    int*   row    = iw + (size_t)n;              // [n+1]
    int*   cur    = iw + (size_t)2 * n + 1;      // [n]
    int*   csr    = iw + (size_t)3 * n + 1;      // [E]
    int*   bsums  = iw + (size_t)3 * n + 1 + E;  // [nb_n] — disjoint from cur
    (void)ws_size; (void)n_in; (void)out_size;

    const int nb_n = (n + NTH - 1) / NTH;        // 196
    const int nb_e = (E + NTH - 1) / NTH;        // 3125

    hipMemsetAsync(cnt, 0, (size_t)n * sizeof(int), stream);

    // layer-1 buffers
    float* xs1 = buf1;  // 16n
    float* ga1 = buf2;  // 16n
    float* h1  = buf3;  // 32n
    float* xs2 = buf1;  // 32n (after xs1 dead)

    // degree + CSR build (dinv/invdeg + xs1 prescale fused into scan1)
    count_kernel<<<nb_e, NTH, 0, stream>>>(dst, E, cnt);
    scan1_kernel<<<nb_n, NTH, 0, stream>>>(cnt, n, bsums, dinv, invdeg, x, xs1);
    scan2_kernel<<<1, NTH, 0, stream>>>(bsums, nb_n);
    scan3_kernel<<<nb_n, NTH, 0, stream>>>(cnt, bsums, n, row, cur);
    fill_kernel<<<nb_e, NTH, 0, stream>>>(src, dst, E, cur, csr);

    // layer 1: aggregate x (16ch) then transform 16->32
    gather_kernel<16, false><<<(n + 63) / 64, NTH, 0, stream>>>(row, csr, xs1, x, dinv, invdeg, nullptr, ga1, n);
    transform_kernel<16, 32, true, true><<<nb_n, NTH, 0, stream>>>(ga1, W1, b1, dinv, h1, xs2, n);

    // layer 2: aggregate h1 (32ch) then transform 32->64
    float* ga2 = buf2;  // 32n
    float* h2  = buf1;  // 64n (xs2 dead after gather)
    gather_kernel<32, false><<<(n + 31) / 32, NTH, 0, stream>>>(row, csr, xs2, h1, dinv, invdeg, nullptr, ga2, n);
    transform_kernel<32, 64, true, false><<<nb_n, NTH, 0, stream>>>(ga2, W2, b2, dinv, h2, nullptr, n);

    // layer 3: transform 64->32 first (t3, ts3), aggregate post-transform, fuse b3+relu
    float* t3  = buf2;                  // 32n
    float* ts3 = buf2 + (size_t)32 * n; // 32n
    float* h3  = buf3;                  // 32n (h1 dead)
    transform_kernel<64, 32, false, true><<<nb_n, NTH, 0, stream>>>(h2, W3, nullptr, dinv, t3, ts3, n);
    gather_kernel<32, true><<<(n + 31) / 32, NTH, 0, stream>>>(row, csr, ts3, t3, dinv, invdeg, b3, h3, n);

    // MLP head: 32 -> 1024 -> 1, j-on-lanes, weights in VGPRs, no LDS
    dim3 mgrid((n + 127) / 128, 8);
    mlp_j_kernel<<<mgrid, MTH, 0, stream>>>(h3, Wf1, bf1, Wf2, part, n);
    sigmoid_kernel<<<nb_n, NTH, 0, stream>>>(part, bf2, out, n);
}

// Round 9
// 214.025 us; speedup vs baseline: 1.4632x; 1.4632x over previous
//
#include <hip/hip_runtime.h>
#include <math.h>

#define C_IN 16
#define NTH 256

typedef __attribute__((ext_vector_type(8))) short bf16x8;
typedef __attribute__((ext_vector_type(4))) float f32x4;

__device__ __forceinline__ unsigned short f2bf(float f) {
    unsigned int u = __float_as_uint(f);
    unsigned int r = (u + 0x7FFFu + ((u >> 16) & 1u)) >> 16;   // RNE
    return (unsigned short)r;
}

// ---------------- degree count (int) ----------------
__global__ __launch_bounds__(NTH) void count_kernel(const int* __restrict__ dst, int E,
                                                    int* __restrict__ cnt) {
    int e = blockIdx.x * NTH + threadIdx.x;
    if (e < E) atomicAdd(&cnt[dst[e]], 1);
}

// ---------------- scan pass 1 + dinv/invdeg + xs1 prescale (fused; node domain) --------
__global__ __launch_bounds__(NTH) void scan1_kernel(const int* __restrict__ cnt, int n,
                                                    int* __restrict__ bsum,
                                                    float* __restrict__ dinv,
                                                    float* __restrict__ invdeg,
                                                    const float* __restrict__ x,
                                                    float* __restrict__ xs) {
    __shared__ int s[NTH];
    int i = blockIdx.x * NTH + threadIdx.x;
    int c = (i < n) ? cnt[i] : 0;
    if (i < n) {
        float d = (float)c + 1.0f;
        float di = rsqrtf(d);
        dinv[i] = di;
        invdeg[i] = 1.0f / d;
        const float4* xv = reinterpret_cast<const float4*>(x + (size_t)i * C_IN);
        float4* xsv = reinterpret_cast<float4*>(xs + (size_t)i * C_IN);
        #pragma unroll
        for (int c4 = 0; c4 < C_IN / 4; ++c4) {
            float4 v = xv[c4];
            v.x *= di; v.y *= di; v.z *= di; v.w *= di;
            xsv[c4] = v;
        }
    }
    s[threadIdx.x] = c;
    __syncthreads();
    for (int off = NTH / 2; off > 0; off >>= 1) {
        if (threadIdx.x < off) s[threadIdx.x] += s[threadIdx.x + off];
        __syncthreads();
    }
    if (threadIdx.x == 0) bsum[blockIdx.x] = s[0];
}

__global__ __launch_bounds__(NTH) void scan2_kernel(int* __restrict__ bsum, int nb) {
    __shared__ int s[NTH];
    int base = 0;
    for (int c = 0; c < nb; c += NTH) {
        int idx = c + threadIdx.x;
        int v = (idx < nb) ? bsum[idx] : 0;
        s[threadIdx.x] = v;
        __syncthreads();
        for (int off = 1; off < NTH; off <<= 1) {
            int x = (threadIdx.x >= off) ? s[threadIdx.x - off] : 0;
            __syncthreads();
            s[threadIdx.x] += x;
            __syncthreads();
        }
        if (idx < nb) bsum[idx] = base + s[threadIdx.x] - v;  // exclusive
        int tot = s[NTH - 1];
        __syncthreads();
        base += tot;
    }
}

__global__ __launch_bounds__(NTH) void scan3_kernel(const int* __restrict__ cnt,
                                                    const int* __restrict__ bsum, int n,
                                                    int* __restrict__ row,
                                                    int* __restrict__ cur) {
    __shared__ int s[NTH];
    int i = blockIdx.x * NTH + threadIdx.x;
    int v = (i < n) ? cnt[i] : 0;
    s[threadIdx.x] = v;
    __syncthreads();
    for (int off = 1; off < NTH; off <<= 1) {
        int x = (threadIdx.x >= off) ? s[threadIdx.x - off] : 0;
        __syncthreads();
        s[threadIdx.x] += x;
        __syncthreads();
    }
    if (i < n) {
        int excl = bsum[blockIdx.x] + s[threadIdx.x] - v;
        row[i] = excl;
        cur[i] = excl;
        if (i == n - 1) row[n] = excl + v;
    }
}

__global__ __launch_bounds__(NTH) void fill_kernel(const int* __restrict__ src,
                                                   const int* __restrict__ dst, int E,
                                                   int* __restrict__ cur,
                                                   int* __restrict__ csr) {
    int e = blockIdx.x * NTH + threadIdx.x;
    if (e < E) {
        int p = atomicAdd(&cur[dst[e]], 1);
        csr[p] = src[e];
    }
}

// ---------------- CSR gather: out[i] = dinv[i]*sum xs[src] + invdeg[i]*self[i] (+b, relu) --
template<int C, bool FINAL>
__global__ __launch_bounds__(NTH) void gather_kernel(const int* __restrict__ row,
                                                     const int* __restrict__ csr,
                                                     const float* __restrict__ xs,
                                                     const float* __restrict__ self,
                                                     const float* __restrict__ dinv,
                                                     const float* __restrict__ invdeg,
                                                     const float* __restrict__ bias,
                                                     float* __restrict__ out, int n) {
    constexpr int G = C / 4;                    // threads per node
    int i = blockIdx.x * (NTH / G) + threadIdx.x / G;
    int q = threadIdx.x % G;
    if (i >= n) return;
    int r0 = row[i], r1 = row[i + 1];
    float4 acc = make_float4(0.f, 0.f, 0.f, 0.f);
    int e = r0;
    for (; e + 7 < r1; e += 8) {
        int s0 = csr[e], s1 = csr[e+1], s2 = csr[e+2], s3 = csr[e+3];
        int s4 = csr[e+4], s5 = csr[e+5], s6 = csr[e+6], s7 = csr[e+7];
        float4 v0 = *reinterpret_cast<const float4*>(xs + (size_t)s0 * C + q * 4);
        float4 v1 = *reinterpret_cast<const float4*>(xs + (size_t)s1 * C + q * 4);
        float4 v2 = *reinterpret_cast<const float4*>(xs + (size_t)s2 * C + q * 4);
        float4 v3 = *reinterpret_cast<const float4*>(xs + (size_t)s3 * C + q * 4);
        float4 v4 = *reinterpret_cast<const float4*>(xs + (size_t)s4 * C + q * 4);
        float4 v5 = *reinterpret_cast<const float4*>(xs + (size_t)s5 * C + q * 4);
        float4 v6 = *reinterpret_cast<const float4*>(xs + (size_t)s6 * C + q * 4);
        float4 v7 = *reinterpret_cast<const float4*>(xs + (size_t)s7 * C + q * 4);
        acc.x += ((v0.x + v1.x) + (v2.x + v3.x)) + ((v4.x + v5.x) + (v6.x + v7.x));
        acc.y += ((v0.y + v1.y) + (v2.y + v3.y)) + ((v4.y + v5.y) + (v6.y + v7.y));
        acc.z += ((v0.z + v1.z) + (v2.z + v3.z)) + ((v4.z + v5.z) + (v6.z + v7.z));
        acc.w += ((v0.w + v1.w) + (v2.w + v3.w)) + ((v4.w + v5.w) + (v6.w + v7.w));
    }
    for (; e + 3 < r1; e += 4) {
        int s0 = csr[e], s1 = csr[e+1], s2 = csr[e+2], s3 = csr[e+3];
        float4 v0 = *reinterpret_cast<const float4*>(xs + (size_t)s0 * C + q * 4);
        float4 v1 = *reinterpret_cast<const float4*>(xs + (size_t)s1 * C + q * 4);
        float4 v2 = *reinterpret_cast<const float4*>(xs + (size_t)s2 * C + q * 4);
        float4 v3 = *reinterpret_cast<const float4*>(xs + (size_t)s3 * C + q * 4);
        acc.x += (v0.x + v1.x) + (v2.x + v3.x);
        acc.y += (v0.y + v1.y) + (v2.y + v3.y);
        acc.z += (v0.z + v1.z) + (v2.z + v3.z);
        acc.w += (v0.w + v1.w) + (v2.w + v3.w);
    }
    for (; e < r1; ++e) {
        int s0 = csr[e];
        float4 v0 = *reinterpret_cast<const float4*>(xs + (size_t)s0 * C + q * 4);
        acc.x += v0.x; acc.y += v0.y; acc.z += v0.z; acc.w += v0.w;
    }
    float di = dinv[i], idg = invdeg[i];
    float4 sv = *reinterpret_cast<const float4*>(self + (size_t)i * C + q * 4);
    float4 o;
    o.x = fmaf(acc.x, di, sv.x * idg);
    o.y = fmaf(acc.y, di, sv.y * idg);
    o.z = fmaf(acc.z, di, sv.z * idg);
    o.w = fmaf(acc.w, di, sv.w * idg);
    if (FINAL) {
        const float4 b = *reinterpret_cast<const float4*>(bias + q * 4);
        o.x = fmaxf(o.x + b.x, 0.f);
        o.y = fmaxf(o.y + b.y, 0.f);
        o.z = fmaxf(o.z + b.z, 0.f);
        o.w = fmaxf(o.w + b.w, 0.f);
    }
    *reinterpret_cast<float4*>(out + (size_t)i * C + q * 4) = o;
}

// ---------------- dense transform: h = [relu](g @ W + b); optional hsc = h * dinv ------
template<int CIN, int COUT, bool BIASRELU, bool WSC>
__global__ __launch_bounds__(NTH) void transform_kernel(const float* __restrict__ g,
                                                        const float* __restrict__ W,
                                                        const float* __restrict__ b,
                                                        const float* __restrict__ dinv,
                                                        float* __restrict__ h,
                                                        float* __restrict__ hsc, int n) {
    __shared__ float Ws[CIN * COUT];
    __shared__ float bs[COUT];
    for (int idx = threadIdx.x; idx < CIN * COUT; idx += NTH) Ws[idx] = W[idx];
    if (BIASRELU && threadIdx.x < COUT) bs[threadIdx.x] = b[threadIdx.x];
    __syncthreads();

    int i = blockIdx.x * NTH + threadIdx.x;
    if (i >= n) return;

    float xr[CIN];
    const float4* xv = reinterpret_cast<const float4*>(g + (size_t)i * CIN);
    #pragma unroll
    for (int k4 = 0; k4 < CIN / 4; ++k4) {
        float4 v = xv[k4];
        xr[k4*4+0] = v.x; xr[k4*4+1] = v.y; xr[k4*4+2] = v.z; xr[k4*4+3] = v.w;
    }

    float di = WSC ? dinv[i] : 0.f;
    float4* hv = reinterpret_cast<float4*>(h + (size_t)i * COUT);
    float4* hscv = WSC ? reinterpret_cast<float4*>(hsc + (size_t)i * COUT) : nullptr;

    #pragma unroll 1
    for (int c4 = 0; c4 < COUT / 4; ++c4) {
        float a0 = 0.f, a1 = 0.f, a2 = 0.f, a3 = 0.f;
        #pragma unroll
        for (int k = 0; k < CIN; ++k) {
            const float4 w = *reinterpret_cast<const float4*>(&Ws[k * COUT + c4 * 4]);
            float xk = xr[k];
            a0 = fmaf(xk, w.x, a0);
            a1 = fmaf(xk, w.y, a1);
            a2 = fmaf(xk, w.z, a2);
            a3 = fmaf(xk, w.w, a3);
        }
        if (BIASRELU) {
            const float4 bv = *reinterpret_cast<const float4*>(&bs[c4 * 4]);
            a0 = fmaxf(a0 + bv.x, 0.f);
            a1 = fmaxf(a1 + bv.y, 0.f);
            a2 = fmaxf(a2 + bv.z, 0.f);
            a3 = fmaxf(a3 + bv.w, 0.f);
        }
        float4 o; o.x = a0; o.y = a1; o.z = a2; o.w = a3;
        hv[c4] = o;
        if (WSC) {
            float4 s; s.x = a0 * di; s.y = a1 * di; s.z = a2 * di; s.w = a3 * di;
            hscv[c4] = s;
        }
    }
}

// ---------------- fused transform2+3: ga2(32) -> relu(·W2+b2)(64) -> ·W3 (32), ×dinv ----
__global__ __launch_bounds__(NTH) void transform23_kernel(const float* __restrict__ g,
                                                          const float* __restrict__ W2,
                                                          const float* __restrict__ b2,
                                                          const float* __restrict__ W3,
                                                          const float* __restrict__ dinv,
                                                          float* __restrict__ t3,
                                                          float* __restrict__ ts3, int n) {
    __shared__ float Ws2[32 * 64];
    __shared__ float Ws3[64 * 32];
    __shared__ float bs2[64];
    for (int idx = threadIdx.x; idx < 2048; idx += NTH) {
        Ws2[idx] = W2[idx];
        Ws3[idx] = W3[idx];
    }
    if (threadIdx.x < 64) bs2[threadIdx.x] = b2[threadIdx.x];
    __syncthreads();

    int i = blockIdx.x * NTH + threadIdx.x;
    if (i >= n) return;

    float xr[32];
    const float4* xv = reinterpret_cast<const float4*>(g + (size_t)i * 32);
    #pragma unroll
    for (int k4 = 0; k4 < 8; ++k4) {
        float4 v = xv[k4];
        xr[k4*4+0] = v.x; xr[k4*4+1] = v.y; xr[k4*4+2] = v.z; xr[k4*4+3] = v.w;
    }

    float hh[64];
    #pragma unroll 1
    for (int c4 = 0; c4 < 16; ++c4) {
        float a0 = 0.f, a1 = 0.f, a2 = 0.f, a3 = 0.f;
        #pragma unroll
        for (int k = 0; k < 32; ++k) {
            const float4 w = *reinterpret_cast<const float4*>(&Ws2[k * 64 + c4 * 4]);
            float xk = xr[k];
            a0 = fmaf(xk, w.x, a0);
            a1 = fmaf(xk, w.y, a1);
            a2 = fmaf(xk, w.z, a2);
            a3 = fmaf(xk, w.w, a3);
        }
        const float4 bv = *reinterpret_cast<const float4*>(&bs2[c4 * 4]);
        hh[c4*4+0] = fmaxf(a0 + bv.x, 0.f);
        hh[c4*4+1] = fmaxf(a1 + bv.y, 0.f);
        hh[c4*4+2] = fmaxf(a2 + bv.z, 0.f);
        hh[c4*4+3] = fmaxf(a3 + bv.w, 0.f);
    }

    float dv = dinv[i];
    float4* t3v = reinterpret_cast<float4*>(t3 + (size_t)i * 32);
    float4* ts3v = reinterpret_cast<float4*>(ts3 + (size_t)i * 32);
    #pragma unroll 1
    for (int c4 = 0; c4 < 8; ++c4) {
        float a0 = 0.f, a1 = 0.f, a2 = 0.f, a3 = 0.f;
        #pragma unroll
        for (int k = 0; k < 64; ++k) {
            const float4 w = *reinterpret_cast<const float4*>(&Ws3[k * 32 + c4 * 4]);
            float hk = hh[k];
            a0 = fmaf(hk, w.x, a0);
            a1 = fmaf(hk, w.y, a1);
            a2 = fmaf(hk, w.z, a2);
            a3 = fmaf(hk, w.w, a3);
        }
        float4 o; o.x = a0; o.y = a1; o.z = a2; o.w = a3;
        t3v[c4] = o;
        float4 s; s.x = a0 * dv; s.y = a1 * dv; s.z = a2 * dv; s.w = a3 * dv;
        ts3v[c4] = s;
    }
}

// ---------------- MLP head via MFMA: [n x 32] @ [32 x 1024] -> relu -> ·Wf2, j-sum -------
// A: row=lane&15, k=(lane>>4)*8+e ; B: col=lane&15, k=(lane>>4)*8+e ;
// D/C: col=lane&15, row=(lane>>4)*4+reg  [m89-verified]. Bias rides in C (col-only dep).
// grid (ceil(n/512), 2): blockIdx.y = j-half (512 hidden units, 32 j-tiles), 4 waves,
// 8 node-tiles (16 nodes) per wave. Wf1 staged once per block in fragment order (bf16).
__global__ __launch_bounds__(NTH, 2) void mlp_mfma_kernel(const float* __restrict__ h3,
                                                          const float* __restrict__ Wf1,
                                                          const float* __restrict__ bf1,
                                                          const float* __restrict__ Wf2,
                                                          float* __restrict__ part, int n) {
    __shared__ unsigned short lds_w[32 * 512];   // 32 KB, [jt][lane][e]
    __shared__ float b1s[512];
    __shared__ float w2s[512];
    const int tid = threadIdx.x;
    const int jh = blockIdx.y;                   // j-half

    for (int idx = tid; idx < 32 * 512; idx += NTH) {
        int k = idx >> 9, jj = idx & 511;        // coalesced over jj
        float wv = Wf1[k * 1024 + jh * 512 + jj];
        int l = ((k >> 3) << 4) | (jj & 15);
        int jt = jj >> 4;
        lds_w[(jt * 64 + l) * 8 + (k & 7)] = f2bf(wv);
    }
    for (int idx = tid; idx < 512; idx += NTH) {
        b1s[idx] = bf1[jh * 512 + idx];
        w2s[idx] = Wf2[jh * 512 + idx];
    }
    __syncthreads();

    const int wid = tid >> 6, lane = tid & 63;
    const int r16 = lane & 15;
    const int kb = (lane >> 4) * 8;
    float* slice = part + (size_t)jh * n;

    #pragma unroll 1
    for (int tt = 0; tt < 8; ++tt) {
        const int i0 = blockIdx.x * 512 + (wid * 8 + tt) * 16;
        const int ia = i0 + r16;

        bf16x8 af;
        if (ia < n) {
            const float4 f0 = *reinterpret_cast<const float4*>(h3 + (size_t)ia * 32 + kb);
            const float4 f1 = *reinterpret_cast<const float4*>(h3 + (size_t)ia * 32 + kb + 4);
            af[0] = (short)f2bf(f0.x); af[1] = (short)f2bf(f0.y);
            af[2] = (short)f2bf(f0.z); af[3] = (short)f2bf(f0.w);
            af[4] = (short)f2bf(f1.x); af[5] = (short)f2bf(f1.y);
            af[6] = (short)f2bf(f1.z); af[7] = (short)f2bf(f1.w);
        } else {
            #pragma unroll
            for (int e = 0; e < 8; ++e) af[e] = 0;
        }

        float p0 = 0.f, p1 = 0.f, p2 = 0.f, p3 = 0.f;
        #pragma unroll 4
        for (int jt = 0; jt < 32; ++jt) {
            const bf16x8 bf = *reinterpret_cast<const bf16x8*>(&lds_w[(jt * 64 + lane) * 8]);
            const float bj = b1s[jt * 16 + r16];
            f32x4 cc; cc[0] = bj; cc[1] = bj; cc[2] = bj; cc[3] = bj;
            f32x4 acc = __builtin_amdgcn_mfma_f32_16x16x32_bf16(af, bf, cc, 0, 0, 0);
            const float gj = w2s[jt * 16 + r16];
            p0 = fmaf(fmaxf(acc[0], 0.f), gj, p0);
            p1 = fmaf(fmaxf(acc[1], 0.f), gj, p1);
            p2 = fmaf(fmaxf(acc[2], 0.f), gj, p2);
            p3 = fmaf(fmaxf(acc[3], 0.f), gj, p3);
        }
        // reduce over the 16 columns (lanes sharing lane>>4)
        #pragma unroll
        for (int m = 1; m < 16; m <<= 1) {
            p0 += __shfl_xor(p0, m, 64);
            p1 += __shfl_xor(p1, m, 64);
            p2 += __shfl_xor(p2, m, 64);
            p3 += __shfl_xor(p3, m, 64);
        }
        if (r16 == 0) {
            const int rbase = i0 + (lane >> 4) * 4;
            if (rbase + 0 < n) slice[rbase + 0] = p0;
            if (rbase + 1 < n) slice[rbase + 1] = p1;
            if (rbase + 2 < n) slice[rbase + 2] = p2;
            if (rbase + 3 < n) slice[rbase + 3] = p3;
        }
    }
}

__global__ __launch_bounds__(NTH) void sigmoid_kernel(const float* __restrict__ part,
                                                      const float* __restrict__ bf2,
                                                      float* __restrict__ out, int n) {
    int i = blockIdx.x * NTH + threadIdx.x;
    if (i < n) {
        float z = bf2[0] + part[i] + part[(size_t)n + i];
        out[i] = 1.0f / (1.0f + expf(-z));
    }
}

extern "C" void kernel_launch(void* const* d_in, const int* in_sizes, int n_in,
                              void* d_out, int out_size, void* d_ws, size_t ws_size,
                              hipStream_t stream) {
    const float* x    = (const float*)d_in[0];
    const int*   ei   = (const int*)d_in[1];
    const float* W1   = (const float*)d_in[2];
    const float* b1   = (const float*)d_in[3];
    const float* W2   = (const float*)d_in[4];
    const float* b2   = (const float*)d_in[5];
    const float* W3   = (const float*)d_in[6];
    const float* b3   = (const float*)d_in[7];
    const float* Wf1  = (const float*)d_in[8];
    const float* bf1  = (const float*)d_in[9];
    const float* Wf2  = (const float*)d_in[10];
    const float* bf2  = (const float*)d_in[11];
    float* out = (float*)d_out;

    const int n = in_sizes[0] / C_IN;          // 50000
    const int E = in_sizes[1] / 2;             // 800000
    const int* src = ei;
    const int* dst = ei + E;

    // ---- workspace layout ----
    float* ws = (float*)d_ws;
    float* dinv   = ws;                          // [n]
    float* invdeg = ws + (size_t)n;              // [n]
    float* part   = ws + (size_t)2 * n;          // [2n]
    float* buf1   = ws + (size_t)18 * n;         // [64n]
    float* buf2   = ws + (size_t)82 * n;         // [64n]
    float* buf3   = ws + (size_t)146 * n;        // [32n]
    int*   iw     = (int*)(ws + (size_t)178 * n);
    int*   cnt    = iw;                          // [n]
    int*   row    = iw + (size_t)n;              // [n+1]
    int*   cur    = iw + (size_t)2 * n + 1;      // [n]
    int*   csr    = iw + (size_t)3 * n + 1;      // [E]
    int*   bsums  = iw + (size_t)3 * n + 1 + E;  // [nb_n] — disjoint from cur
    (void)ws_size; (void)n_in; (void)out_size;

    const int nb_n = (n + NTH - 1) / NTH;        // 196
    const int nb_e = (E + NTH - 1) / NTH;        // 3125

    hipMemsetAsync(cnt, 0, (size_t)n * sizeof(int), stream);

    // layer-1 buffers
    float* xs1 = buf1;  // 16n
    float* ga1 = buf2;  // 16n
    float* h1  = buf3;  // 32n
    float* xs2 = buf1;  // 32n (after xs1 dead)

    // degree + CSR build (dinv/invdeg + xs1 prescale fused into scan1)
    count_kernel<<<nb_e, NTH, 0, stream>>>(dst, E, cnt);
    scan1_kernel<<<nb_n, NTH, 0, stream>>>(cnt, n, bsums, dinv, invdeg, x, xs1);
    scan2_kernel<<<1, NTH, 0, stream>>>(bsums, nb_n);
    scan3_kernel<<<nb_n, NTH, 0, stream>>>(cnt, bsums, n, row, cur);
    fill_kernel<<<nb_e, NTH, 0, stream>>>(src, dst, E, cur, csr);

    // layer 1: aggregate x (16ch) then transform 16->32
    gather_kernel<16, false><<<(n + 63) / 64, NTH, 0, stream>>>(row, csr, xs1, x, dinv, invdeg, nullptr, ga1, n);
    transform_kernel<16, 32, true, true><<<nb_n, NTH, 0, stream>>>(ga1, W1, b1, dinv, h1, xs2, n);

    // layer 2: aggregate h1 (32ch), then fused transform 32->64->32 (t3 raw, ts3 = t3*dinv)
    float* ga2 = buf2;                   // 32n
    gather_kernel<32, false><<<(n + 31) / 32, NTH, 0, stream>>>(row, csr, xs2, h1, dinv, invdeg, nullptr, ga2, n);
    float* t3  = buf1;                   // 32n (xs2 dead)
    float* ts3 = buf1 + (size_t)32 * n;  // 32n
    transform23_kernel<<<nb_n, NTH, 0, stream>>>(ga2, W2, b2, W3, dinv, t3, ts3, n);

    // layer 3 aggregation (post-transform), fuse b3+relu -> h3
    float* h3 = buf3;                    // 32n (h1 dead)
    gather_kernel<32, true><<<(n + 31) / 32, NTH, 0, stream>>>(row, csr, ts3, t3, dinv, invdeg, b3, h3, n);

    // MLP head: MFMA GEMM + fused relu/fc2/j-reduction -> 2 partials, then sigmoid
    dim3 mgrid((n + 511) / 512, 2);
    mlp_mfma_kernel<<<mgrid, NTH, 0, stream>>>(h3, Wf1, bf1, Wf2, part, n);
    sigmoid_kernel<<<nb_n, NTH, 0, stream>>>(part, bf2, out, n);
}

// Round 10
// 176.458 us; speedup vs baseline: 1.7747x; 1.2129x over previous
//
#include <hip/hip_runtime.h>
#include <math.h>

#define C_IN 16
#define NTH 256
#define BKT_SHIFT 8            // 256 nodes per bucket
#define NBK_MAX 1024

typedef __attribute__((ext_vector_type(8))) short bf16x8;
typedef __attribute__((ext_vector_type(4))) float f32x4;

__device__ __forceinline__ unsigned short f2bf(float f) {
    unsigned int u = __float_as_uint(f);
    unsigned int r = (u + 0x7FFFu + ((u >> 16) & 1u)) >> 16;   // RNE
    return (unsigned short)r;
}

// ---------------- bucket histogram (128 fat blocks, LDS hist, few global atomics) ------
__global__ __launch_bounds__(NTH) void bkt_hist_kernel(const int* __restrict__ dst, int E,
                                                       int nbk, int* __restrict__ bcnt) {
    __shared__ int h[NBK_MAX];
    for (int i = threadIdx.x; i < nbk; i += NTH) h[i] = 0;
    __syncthreads();
    for (int e = blockIdx.x * NTH + threadIdx.x; e < E; e += gridDim.x * NTH)
        atomicAdd(&h[dst[e] >> BKT_SHIFT], 1);
    __syncthreads();
    for (int i = threadIdx.x; i < nbk; i += NTH)
        if (h[i]) atomicAdd(&bcnt[i], h[i]);
}

// ---------------- bucket scan (1 block; nbk <= 1024, serial in lane 0 is fine) ---------
__global__ __launch_bounds__(NTH) void bkt_scan_kernel(const int* __restrict__ bcnt, int nbk,
                                                       int* __restrict__ bbase,
                                                       int* __restrict__ bcur) {
    __shared__ int s[NBK_MAX + 1];
    for (int i = threadIdx.x; i < nbk; i += NTH) s[i] = bcnt[i];
    __syncthreads();
    if (threadIdx.x == 0) {
        int acc = 0;
        for (int i = 0; i < nbk; ++i) { int v = s[i]; s[i] = acc; acc += v; }
        s[nbk] = acc;
    }
    __syncthreads();
    for (int i = threadIdx.x; i <= nbk; i += NTH) bbase[i] = s[i];
    for (int i = threadIdx.x; i < nbk; i += NTH) bcur[i] = s[i];
}

// ---------------- bucket scatter: append (src,dst) into per-bucket regions -------------
// Per block: LDS hist over its edge chunk -> one global atomic per bucket to reserve ->
// re-read chunk, place via LDS cursors. Writes go to ~nbk hot tail lines -> no write amp.
__global__ __launch_bounds__(NTH) void bkt_scatter_kernel(const int* __restrict__ src,
                                                          const int* __restrict__ dst, int E,
                                                          int nbk, int* __restrict__ bcur,
                                                          int2* __restrict__ pairs) {
    __shared__ int h[NBK_MAX];
    __shared__ int base[NBK_MAX];
    const int chunk = (E + gridDim.x - 1) / gridDim.x;
    const int e0 = blockIdx.x * chunk;
    const int e1 = min(e0 + chunk, E);

    for (int i = threadIdx.x; i < nbk; i += NTH) h[i] = 0;
    __syncthreads();
    for (int e = e0 + threadIdx.x; e < e1; e += NTH)
        atomicAdd(&h[dst[e] >> BKT_SHIFT], 1);
    __syncthreads();
    for (int i = threadIdx.x; i < nbk; i += NTH) {
        int c = h[i];
        base[i] = c ? atomicAdd(&bcur[i], c) : 0;
    }
    __syncthreads();
    for (int i = threadIdx.x; i < nbk; i += NTH) h[i] = 0;
    __syncthreads();
    for (int e = e0 + threadIdx.x; e < e1; e += NTH) {
        int d = dst[e];
        int b = d >> BKT_SHIFT;
        int p = base[b] + atomicAdd(&h[b], 1);
        pairs[p] = make_int2(src[e], d);
    }
}

// ---------------- per-bucket node count: exclusive dst-range ownership, no atomics -----
__global__ __launch_bounds__(NTH) void bucket_count_kernel(const int2* __restrict__ pairs,
                                                           const int* __restrict__ bbase,
                                                           int n, int* __restrict__ cnt) {
    __shared__ int h[256];
    h[threadIdx.x] = 0;
    __syncthreads();
    const int b = blockIdx.x;
    const int p0 = bbase[b], p1 = bbase[b + 1];
    for (int p = p0 + threadIdx.x; p < p1; p += NTH)
        atomicAdd(&h[pairs[p].y & 255], 1);
    __syncthreads();
    int gi = b * 256 + threadIdx.x;
    if (gi < n) cnt[gi] = h[threadIdx.x];
}

// ---------------- per-bucket CSR fill with LDS cursors (localized writes) --------------
__global__ __launch_bounds__(NTH) void fill_local_kernel(const int2* __restrict__ pairs,
                                                         const int* __restrict__ bbase,
                                                         const int* __restrict__ row,
                                                         int n, int* __restrict__ csr) {
    __shared__ int curL[256];
    const int b = blockIdx.x;
    int gi = b * 256 + threadIdx.x;
    curL[threadIdx.x] = (gi < n) ? row[gi] : 0;
    __syncthreads();
    const int p0 = bbase[b], p1 = bbase[b + 1];
    for (int p = p0 + threadIdx.x; p < p1; p += NTH) {
        int2 pr = pairs[p];
        int pos = atomicAdd(&curL[pr.y & 255], 1);
        csr[pos] = pr.x;
    }
}

// ---------------- scan pass 1 + dinv/invdeg + xs1 prescale (fused; node domain) --------
__global__ __launch_bounds__(NTH) void scan1_kernel(const int* __restrict__ cnt, int n,
                                                    int* __restrict__ bsum,
                                                    float* __restrict__ dinv,
                                                    float* __restrict__ invdeg,
                                                    const float* __restrict__ x,
                                                    float* __restrict__ xs) {
    __shared__ int s[NTH];
    int i = blockIdx.x * NTH + threadIdx.x;
    int c = (i < n) ? cnt[i] : 0;
    if (i < n) {
        float d = (float)c + 1.0f;
        float di = rsqrtf(d);
        dinv[i] = di;
        invdeg[i] = 1.0f / d;
        const float4* xv = reinterpret_cast<const float4*>(x + (size_t)i * C_IN);
        float4* xsv = reinterpret_cast<float4*>(xs + (size_t)i * C_IN);
        #pragma unroll
        for (int c4 = 0; c4 < C_IN / 4; ++c4) {
            float4 v = xv[c4];
            v.x *= di; v.y *= di; v.z *= di; v.w *= di;
            xsv[c4] = v;
        }
    }
    s[threadIdx.x] = c;
    __syncthreads();
    for (int off = NTH / 2; off > 0; off >>= 1) {
        if (threadIdx.x < off) s[threadIdx.x] += s[threadIdx.x + off];
        __syncthreads();
    }
    if (threadIdx.x == 0) bsum[blockIdx.x] = s[0];
}

__global__ __launch_bounds__(NTH) void scan2_kernel(int* __restrict__ bsum, int nb) {
    __shared__ int s[NTH];
    int base = 0;
    for (int c = 0; c < nb; c += NTH) {
        int idx = c + threadIdx.x;
        int v = (idx < nb) ? bsum[idx] : 0;
        s[threadIdx.x] = v;
        __syncthreads();
        for (int off = 1; off < NTH; off <<= 1) {
            int x = (threadIdx.x >= off) ? s[threadIdx.x - off] : 0;
            __syncthreads();
            s[threadIdx.x] += x;
            __syncthreads();
        }
        if (idx < nb) bsum[idx] = base + s[threadIdx.x] - v;  // exclusive
        int tot = s[NTH - 1];
        __syncthreads();
        base += tot;
    }
}

__global__ __launch_bounds__(NTH) void scan3_kernel(const int* __restrict__ cnt,
                                                    const int* __restrict__ bsum, int n,
                                                    int* __restrict__ row) {
    __shared__ int s[NTH];
    int i = blockIdx.x * NTH + threadIdx.x;
    int v = (i < n) ? cnt[i] : 0;
    s[threadIdx.x] = v;
    __syncthreads();
    for (int off = 1; off < NTH; off <<= 1) {
        int x = (threadIdx.x >= off) ? s[threadIdx.x - off] : 0;
        __syncthreads();
        s[threadIdx.x] += x;
        __syncthreads();
    }
    if (i < n) {
        int excl = bsum[blockIdx.x] + s[threadIdx.x] - v;
        row[i] = excl;
        if (i == n - 1) row[n] = excl + v;
    }
}

// ---------------- CSR gather: out[i] = dinv[i]*sum xs[src] + invdeg[i]*self[i] (+b, relu) --
template<int C, bool FINAL>
__global__ __launch_bounds__(NTH) void gather_kernel(const int* __restrict__ row,
                                                     const int* __restrict__ csr,
                                                     const float* __restrict__ xs,
                                                     const float* __restrict__ self,
                                                     const float* __restrict__ dinv,
                                                     const float* __restrict__ invdeg,
                                                     const float* __restrict__ bias,
                                                     float* __restrict__ out, int n) {
    constexpr int G = C / 4;                    // threads per node
    int i = blockIdx.x * (NTH / G) + threadIdx.x / G;
    int q = threadIdx.x % G;
    if (i >= n) return;
    int r0 = row[i], r1 = row[i + 1];
    float4 acc = make_float4(0.f, 0.f, 0.f, 0.f);
    int e = r0;
    for (; e + 7 < r1; e += 8) {
        int s0 = csr[e], s1 = csr[e+1], s2 = csr[e+2], s3 = csr[e+3];
        int s4 = csr[e+4], s5 = csr[e+5], s6 = csr[e+6], s7 = csr[e+7];
        float4 v0 = *reinterpret_cast<const float4*>(xs + (size_t)s0 * C + q * 4);
        float4 v1 = *reinterpret_cast<const float4*>(xs + (size_t)s1 * C + q * 4);
        float4 v2 = *reinterpret_cast<const float4*>(xs + (size_t)s2 * C + q * 4);
        float4 v3 = *reinterpret_cast<const float4*>(xs + (size_t)s3 * C + q * 4);
        float4 v4 = *reinterpret_cast<const float4*>(xs + (size_t)s4 * C + q * 4);
        float4 v5 = *reinterpret_cast<const float4*>(xs + (size_t)s5 * C + q * 4);
        float4 v6 = *reinterpret_cast<const float4*>(xs + (size_t)s6 * C + q * 4);
        float4 v7 = *reinterpret_cast<const float4*>(xs + (size_t)s7 * C + q * 4);
        acc.x += ((v0.x + v1.x) + (v2.x + v3.x)) + ((v4.x + v5.x) + (v6.x + v7.x));
        acc.y += ((v0.y + v1.y) + (v2.y + v3.y)) + ((v4.y + v5.y) + (v6.y + v7.y));
        acc.z += ((v0.z + v1.z) + (v2.z + v3.z)) + ((v4.z + v5.z) + (v6.z + v7.z));
        acc.w += ((v0.w + v1.w) + (v2.w + v3.w)) + ((v4.w + v5.w) + (v6.w + v7.w));
    }
    for (; e + 3 < r1; e += 4) {
        int s0 = csr[e], s1 = csr[e+1], s2 = csr[e+2], s3 = csr[e+3];
        float4 v0 = *reinterpret_cast<const float4*>(xs + (size_t)s0 * C + q * 4);
        float4 v1 = *reinterpret_cast<const float4*>(xs + (size_t)s1 * C + q * 4);
        float4 v2 = *reinterpret_cast<const float4*>(xs + (size_t)s2 * C + q * 4);
        float4 v3 = *reinterpret_cast<const float4*>(xs + (size_t)s3 * C + q * 4);
        acc.x += (v0.x + v1.x) + (v2.x + v3.x);
        acc.y += (v0.y + v1.y) + (v2.y + v3.y);
        acc.z += (v0.z + v1.z) + (v2.z + v3.z);
        acc.w += (v0.w + v1.w) + (v2.w + v3.w);
    }
    for (; e < r1; ++e) {
        int s0 = csr[e];
        float4 v0 = *reinterpret_cast<const float4*>(xs + (size_t)s0 * C + q * 4);
        acc.x += v0.x; acc.y += v0.y; acc.z += v0.z; acc.w += v0.w;
    }
    float di = dinv[i], idg = invdeg[i];
    float4 sv = *reinterpret_cast<const float4*>(self + (size_t)i * C + q * 4);
    float4 o;
    o.x = fmaf(acc.x, di, sv.x * idg);
    o.y = fmaf(acc.y, di, sv.y * idg);
    o.z = fmaf(acc.z, di, sv.z * idg);
    o.w = fmaf(acc.w, di, sv.w * idg);
    if (FINAL) {
        const float4 b = *reinterpret_cast<const float4*>(bias + q * 4);
        o.x = fmaxf(o.x + b.x, 0.f);
        o.y = fmaxf(o.y + b.y, 0.f);
        o.z = fmaxf(o.z + b.z, 0.f);
        o.w = fmaxf(o.w + b.w, 0.f);
    }
    *reinterpret_cast<float4*>(out + (size_t)i * C + q * 4) = o;
}

// ---------------- dense transform: h = [relu](g @ W + b); optional hsc = h * dinv ------
template<int CIN, int COUT, bool BIASRELU, bool WSC>
__global__ __launch_bounds__(NTH) void transform_kernel(const float* __restrict__ g,
                                                        const float* __restrict__ W,
                                                        const float* __restrict__ b,
                                                        const float* __restrict__ dinv,
                                                        float* __restrict__ h,
                                                        float* __restrict__ hsc, int n) {
    __shared__ float Ws[CIN * COUT];
    __shared__ float bs[COUT];
    for (int idx = threadIdx.x; idx < CIN * COUT; idx += NTH) Ws[idx] = W[idx];
    if (BIASRELU && threadIdx.x < COUT) bs[threadIdx.x] = b[threadIdx.x];
    __syncthreads();

    int i = blockIdx.x * NTH + threadIdx.x;
    if (i >= n) return;

    float xr[CIN];
    const float4* xv = reinterpret_cast<const float4*>(g + (size_t)i * CIN);
    #pragma unroll
    for (int k4 = 0; k4 < CIN / 4; ++k4) {
        float4 v = xv[k4];
        xr[k4*4+0] = v.x; xr[k4*4+1] = v.y; xr[k4*4+2] = v.z; xr[k4*4+3] = v.w;
    }

    float di = WSC ? dinv[i] : 0.f;
    float4* hv = reinterpret_cast<float4*>(h + (size_t)i * COUT);
    float4* hscv = WSC ? reinterpret_cast<float4*>(hsc + (size_t)i * COUT) : nullptr;

    #pragma unroll 1
    for (int c4 = 0; c4 < COUT / 4; ++c4) {
        float a0 = 0.f, a1 = 0.f, a2 = 0.f, a3 = 0.f;
        #pragma unroll
        for (int k = 0; k < CIN; ++k) {
            const float4 w = *reinterpret_cast<const float4*>(&Ws[k * COUT + c4 * 4]);
            float xk = xr[k];
            a0 = fmaf(xk, w.x, a0);
            a1 = fmaf(xk, w.y, a1);
            a2 = fmaf(xk, w.z, a2);
            a3 = fmaf(xk, w.w, a3);
        }
        if (BIASRELU) {
            const float4 bv = *reinterpret_cast<const float4*>(&bs[c4 * 4]);
            a0 = fmaxf(a0 + bv.x, 0.f);
            a1 = fmaxf(a1 + bv.y, 0.f);
            a2 = fmaxf(a2 + bv.z, 0.f);
            a3 = fmaxf(a3 + bv.w, 0.f);
        }
        float4 o; o.x = a0; o.y = a1; o.z = a2; o.w = a3;
        hv[c4] = o;
        if (WSC) {
            float4 s; s.x = a0 * di; s.y = a1 * di; s.z = a2 * di; s.w = a3 * di;
            hscv[c4] = s;
        }
    }
}

// ---------------- fused transform2+3: ga2(32) -> relu(·W2+b2)(64) -> ·W3 (32), ×dinv ----
__global__ __launch_bounds__(NTH) void transform23_kernel(const float* __restrict__ g,
                                                          const float* __restrict__ W2,
                                                          const float* __restrict__ b2,
                                                          const float* __restrict__ W3,
                                                          const float* __restrict__ dinv,
                                                          float* __restrict__ t3,
                                                          float* __restrict__ ts3, int n) {
    __shared__ float Ws2[32 * 64];
    __shared__ float Ws3[64 * 32];
    __shared__ float bs2[64];
    for (int idx = threadIdx.x; idx < 2048; idx += NTH) {
        Ws2[idx] = W2[idx];
        Ws3[idx] = W3[idx];
    }
    if (threadIdx.x < 64) bs2[threadIdx.x] = b2[threadIdx.x];
    __syncthreads();

    int i = blockIdx.x * NTH + threadIdx.x;
    if (i >= n) return;

    float xr[32];
    const float4* xv = reinterpret_cast<const float4*>(g + (size_t)i * 32);
    #pragma unroll
    for (int k4 = 0; k4 < 8; ++k4) {
        float4 v = xv[k4];
        xr[k4*4+0] = v.x; xr[k4*4+1] = v.y; xr[k4*4+2] = v.z; xr[k4*4+3] = v.w;
    }

    float hh[64];
    #pragma unroll 1
    for (int c4 = 0; c4 < 16; ++c4) {
        float a0 = 0.f, a1 = 0.f, a2 = 0.f, a3 = 0.f;
        #pragma unroll
        for (int k = 0; k < 32; ++k) {
            const float4 w = *reinterpret_cast<const float4*>(&Ws2[k * 64 + c4 * 4]);
            float xk = xr[k];
            a0 = fmaf(xk, w.x, a0);
            a1 = fmaf(xk, w.y, a1);
            a2 = fmaf(xk, w.z, a2);
            a3 = fmaf(xk, w.w, a3);
        }
        const float4 bv = *reinterpret_cast<const float4*>(&bs2[c4 * 4]);
        hh[c4*4+0] = fmaxf(a0 + bv.x, 0.f);
        hh[c4*4+1] = fmaxf(a1 + bv.y, 0.f);
        hh[c4*4+2] = fmaxf(a2 + bv.z, 0.f);
        hh[c4*4+3] = fmaxf(a3 + bv.w, 0.f);
    }

    float dv = dinv[i];
    float4* t3v = reinterpret_cast<float4*>(t3 + (size_t)i * 32);
    float4* ts3v = reinterpret_cast<float4*>(ts3 + (size_t)i * 32);
    #pragma unroll 1
    for (int c4 = 0; c4 < 8; ++c4) {
        float a0 = 0.f, a1 = 0.f, a2 = 0.f, a3 = 0.f;
        #pragma unroll
        for (int k = 0; k < 64; ++k) {
            const float4 w = *reinterpret_cast<const float4*>(&Ws3[k * 32 + c4 * 4]);
            float hk = hh[k];
            a0 = fmaf(hk, w.x, a0);
            a1 = fmaf(hk, w.y, a1);
            a2 = fmaf(hk, w.z, a2);
            a3 = fmaf(hk, w.w, a3);
        }
        float4 o; o.x = a0; o.y = a1; o.z = a2; o.w = a3;
        t3v[c4] = o;
        float4 s; s.x = a0 * dv; s.y = a1 * dv; s.z = a2 * dv; s.w = a3 * dv;
        ts3v[c4] = s;
    }
}

// ---------------- MLP head via MFMA (layouts m89-verified; bias rides in C) ------------
__global__ __launch_bounds__(NTH, 2) void mlp_mfma_kernel(const float* __restrict__ h3,
                                                          const float* __restrict__ Wf1,
                                                          const float* __restrict__ bf1,
                                                          const float* __restrict__ Wf2,
                                                          float* __restrict__ part, int n) {
    __shared__ unsigned short lds_w[32 * 512];   // 32 KB, [jt][lane][e]
    __shared__ float b1s[512];
    __shared__ float w2s[512];
    const int tid = threadIdx.x;
    const int jh = blockIdx.y;                   // j-half

    for (int idx = tid; idx < 32 * 512; idx += NTH) {
        int k = idx >> 9, jj = idx & 511;        // coalesced over jj
        float wv = Wf1[k * 1024 + jh * 512 + jj];
        int l = ((k >> 3) << 4) | (jj & 15);
        int jt = jj >> 4;
        lds_w[(jt * 64 + l) * 8 + (k & 7)] = f2bf(wv);
    }
    for (int idx = tid; idx < 512; idx += NTH) {
        b1s[idx] = bf1[jh * 512 + idx];
        w2s[idx] = Wf2[jh * 512 + idx];
    }
    __syncthreads();

    const int wid = tid >> 6, lane = tid & 63;
    const int r16 = lane & 15;
    const int kb = (lane >> 4) * 8;
    float* slice = part + (size_t)jh * n;

    #pragma unroll 1
    for (int tt = 0; tt < 8; ++tt) {
        const int i0 = blockIdx.x * 512 + (wid * 8 + tt) * 16;
        const int ia = i0 + r16;

        bf16x8 af;
        if (ia < n) {
            const float4 f0 = *reinterpret_cast<const float4*>(h3 + (size_t)ia * 32 + kb);
            const float4 f1 = *reinterpret_cast<const float4*>(h3 + (size_t)ia * 32 + kb + 4);
            af[0] = (short)f2bf(f0.x); af[1] = (short)f2bf(f0.y);
            af[2] = (short)f2bf(f0.z); af[3] = (short)f2bf(f0.w);
            af[4] = (short)f2bf(f1.x); af[5] = (short)f2bf(f1.y);
            af[6] = (short)f2bf(f1.z); af[7] = (short)f2bf(f1.w);
        } else {
            #pragma unroll
            for (int e = 0; e < 8; ++e) af[e] = 0;
        }

        float p0 = 0.f, p1 = 0.f, p2 = 0.f, p3 = 0.f;
        #pragma unroll 4
        for (int jt = 0; jt < 32; ++jt) {
            const bf16x8 bf = *reinterpret_cast<const bf16x8*>(&lds_w[(jt * 64 + lane) * 8]);
            const float bj = b1s[jt * 16 + r16];
            f32x4 cc; cc[0] = bj; cc[1] = bj; cc[2] = bj; cc[3] = bj;
            f32x4 acc = __builtin_amdgcn_mfma_f32_16x16x32_bf16(af, bf, cc, 0, 0, 0);
            const float gj = w2s[jt * 16 + r16];
            p0 = fmaf(fmaxf(acc[0], 0.f), gj, p0);
            p1 = fmaf(fmaxf(acc[1], 0.f), gj, p1);
            p2 = fmaf(fmaxf(acc[2], 0.f), gj, p2);
            p3 = fmaf(fmaxf(acc[3], 0.f), gj, p3);
        }
        #pragma unroll
        for (int m = 1; m < 16; m <<= 1) {
            p0 += __shfl_xor(p0, m, 64);
            p1 += __shfl_xor(p1, m, 64);
            p2 += __shfl_xor(p2, m, 64);
            p3 += __shfl_xor(p3, m, 64);
        }
        if (r16 == 0) {
            const int rbase = i0 + (lane >> 4) * 4;
            if (rbase + 0 < n) slice[rbase + 0] = p0;
            if (rbase + 1 < n) slice[rbase + 1] = p1;
            if (rbase + 2 < n) slice[rbase + 2] = p2;
            if (rbase + 3 < n) slice[rbase + 3] = p3;
        }
    }
}

__global__ __launch_bounds__(NTH) void sigmoid_kernel(const float* __restrict__ part,
                                                      const float* __restrict__ bf2,
                                                      float* __restrict__ out, int n) {
    int i = blockIdx.x * NTH + threadIdx.x;
    if (i < n) {
        float z = bf2[0] + part[i] + part[(size_t)n + i];
        out[i] = 1.0f / (1.0f + expf(-z));
    }
}

extern "C" void kernel_launch(void* const* d_in, const int* in_sizes, int n_in,
                              void* d_out, int out_size, void* d_ws, size_t ws_size,
                              hipStream_t stream) {
    const float* x    = (const float*)d_in[0];
    const int*   ei   = (const int*)d_in[1];
    const float* W1   = (const float*)d_in[2];
    const float* b1   = (const float*)d_in[3];
    const float* W2   = (const float*)d_in[4];
    const float* b2   = (const float*)d_in[5];
    const float* W3   = (const float*)d_in[6];
    const float* b3   = (const float*)d_in[7];
    const float* Wf1  = (const float*)d_in[8];
    const float* bf1  = (const float*)d_in[9];
    const float* Wf2  = (const float*)d_in[10];
    const float* bf2  = (const float*)d_in[11];
    float* out = (float*)d_out;

    const int n = in_sizes[0] / C_IN;          // 50000
    const int E = in_sizes[1] / 2;             // 800000
    const int* src = ei;
    const int* dst = ei + E;
    const int nbk = (n + 255) >> BKT_SHIFT;    // 196 buckets

    // ---- workspace layout ----
    float* ws = (float*)d_ws;
    float* dinv   = ws;                          // [n]
    float* invdeg = ws + (size_t)n;              // [n]
    float* part   = ws + (size_t)2 * n;          // [2n]
    float* buf1   = ws + (size_t)18 * n;         // [64n]
    float* buf2   = ws + (size_t)82 * n;         // [64n]
    float* buf3   = ws + (size_t)146 * n;        // [32n]
    int*   iw     = (int*)(ws + (size_t)178 * n);
    int*   cnt    = iw;                          // [n]
    int*   row    = iw + (size_t)n;              // [n+1]
    int*   csr    = iw + (size_t)2 * n + 1;      // [E]
    int*   bsums  = iw + (size_t)2 * n + 1 + E;  // [nb_n]
    int*   bcnt   = bsums + 256;                 // [NBK_MAX]
    int*   bbase  = bcnt + NBK_MAX;              // [NBK_MAX+1]
    int*   bcur   = bbase + NBK_MAX + 1;         // [NBK_MAX]
    // pairs aliases buf2: only live between bkt_scatter and fill_local; buf2 (ga1)
    // is first written by gather<16>, which launches after fill_local (stream-ordered).
    int2*  pairs  = (int2*)buf2;                 // [E] = 6.4 MB <= 12.8 MB
    (void)ws_size; (void)n_in; (void)out_size;

    const int nb_n = (n + NTH - 1) / NTH;        // 196

    hipMemsetAsync(bcnt, 0, NBK_MAX * sizeof(int), stream);

    // ---- bucketed CSR build (write-amplification-free) ----
    bkt_hist_kernel<<<128, NTH, 0, stream>>>(dst, E, nbk, bcnt);
    bkt_scan_kernel<<<1, NTH, 0, stream>>>(bcnt, nbk, bbase, bcur);
    bkt_scatter_kernel<<<128, NTH, 0, stream>>>(src, dst, E, nbk, bcur, pairs);
    bucket_count_kernel<<<nbk, NTH, 0, stream>>>(pairs, bbase, n, cnt);

    // layer-1 buffers
    float* xs1 = buf1;  // 16n
    float* ga1 = buf2;  // 16n (after pairs dead)
    float* h1  = buf3;  // 32n
    float* xs2 = buf1;  // 32n (after xs1 dead)

    scan1_kernel<<<nb_n, NTH, 0, stream>>>(cnt, n, bsums, dinv, invdeg, x, xs1);
    scan2_kernel<<<1, NTH, 0, stream>>>(bsums, nb_n);
    scan3_kernel<<<nb_n, NTH, 0, stream>>>(cnt, bsums, n, row);
    fill_local_kernel<<<nbk, NTH, 0, stream>>>(pairs, bbase, row, n, csr);

    // layer 1: aggregate x (16ch) then transform 16->32
    gather_kernel<16, false><<<(n + 63) / 64, NTH, 0, stream>>>(row, csr, xs1, x, dinv, invdeg, nullptr, ga1, n);
    transform_kernel<16, 32, true, true><<<nb_n, NTH, 0, stream>>>(ga1, W1, b1, dinv, h1, xs2, n);

    // layer 2: aggregate h1 (32ch), then fused transform 32->64->32 (t3 raw, ts3 = t3*dinv)
    float* ga2 = buf2;                   // 32n
    gather_kernel<32, false><<<(n + 31) / 32, NTH, 0, stream>>>(row, csr, xs2, h1, dinv, invdeg, nullptr, ga2, n);
    float* t3  = buf1;                   // 32n (xs2 dead)
    float* ts3 = buf1 + (size_t)32 * n;  // 32n
    transform23_kernel<<<nb_n, NTH, 0, stream>>>(ga2, W2, b2, W3, dinv, t3, ts3, n);

    // layer 3 aggregation (post-transform), fuse b3+relu -> h3
    float* h3 = buf3;                    // 32n (h1 dead)
    gather_kernel<32, true><<<(n + 31) / 32, NTH, 0, stream>>>(row, csr, ts3, t3, dinv, invdeg, b3, h3, n);

    // MLP head: MFMA GEMM + fused relu/fc2/j-reduction -> 2 partials, then sigmoid
    dim3 mgrid((n + 511) / 512, 2);
    mlp_mfma_kernel<<<mgrid, NTH, 0, stream>>>(h3, Wf1, bf1, Wf2, part, n);
    sigmoid_kernel<<<nb_n, NTH, 0, stream>>>(part, bf2, out, n);
}

// Round 11
// 169.242 us; speedup vs baseline: 1.8504x; 1.0426x over previous
//
#include <hip/hip_runtime.h>
#include <math.h>

#define C_IN 16
#define NTH 256
#define BKT_SHIFT 8            // 256 nodes per bucket
#define NBK_MAX 1024

typedef __attribute__((ext_vector_type(8))) short bf16x8;
typedef __attribute__((ext_vector_type(4))) float f32x4;

__device__ __forceinline__ unsigned short f2bf(float f) {
    unsigned int u = __float_as_uint(f);
    unsigned int r = (u + 0x7FFFu + ((u >> 16) & 1u)) >> 16;   // RNE
    return (unsigned short)r;
}

// ---------------- bucket histogram (128 fat blocks, LDS hist, few global atomics) ------
__global__ __launch_bounds__(NTH) void bkt_hist_kernel(const int* __restrict__ dst, int E,
                                                       int nbk, int* __restrict__ bcnt) {
    __shared__ int h[NBK_MAX];
    for (int i = threadIdx.x; i < nbk; i += NTH) h[i] = 0;
    __syncthreads();
    for (int e = blockIdx.x * NTH + threadIdx.x; e < E; e += gridDim.x * NTH)
        atomicAdd(&h[dst[e] >> BKT_SHIFT], 1);
    __syncthreads();
    for (int i = threadIdx.x; i < nbk; i += NTH)
        if (h[i]) atomicAdd(&bcnt[i], h[i]);
}

// ---------------- bucket scan (1 block); also writes row[n] = E ------------------------
__global__ __launch_bounds__(NTH) void bkt_scan_kernel(const int* __restrict__ bcnt, int nbk,
                                                       int* __restrict__ bbase,
                                                       int* __restrict__ bcur,
                                                       int* __restrict__ row, int n) {
    __shared__ int s[NBK_MAX + 1];
    for (int i = threadIdx.x; i < nbk; i += NTH) s[i] = bcnt[i];
    __syncthreads();
    if (threadIdx.x == 0) {
        int acc = 0;
        for (int i = 0; i < nbk; ++i) { int v = s[i]; s[i] = acc; acc += v; }
        s[nbk] = acc;
        row[n] = acc;                      // total edge count
    }
    __syncthreads();
    for (int i = threadIdx.x; i <= nbk; i += NTH) bbase[i] = s[i];
    for (int i = threadIdx.x; i < nbk; i += NTH) bcur[i] = s[i];
}

// ---------------- bucket scatter: append (src,dst) into per-bucket regions -------------
__global__ __launch_bounds__(NTH) void bkt_scatter_kernel(const int* __restrict__ src,
                                                          const int* __restrict__ dst, int E,
                                                          int nbk, int* __restrict__ bcur,
                                                          int2* __restrict__ pairs) {
    __shared__ int h[NBK_MAX];
    __shared__ int base[NBK_MAX];
    const int chunk = (E + gridDim.x - 1) / gridDim.x;
    const int e0 = blockIdx.x * chunk;
    const int e1 = min(e0 + chunk, E);

    for (int i = threadIdx.x; i < nbk; i += NTH) h[i] = 0;
    __syncthreads();
    for (int e = e0 + threadIdx.x; e < e1; e += NTH)
        atomicAdd(&h[dst[e] >> BKT_SHIFT], 1);
    __syncthreads();
    for (int i = threadIdx.x; i < nbk; i += NTH) {
        int c = h[i];
        base[i] = c ? atomicAdd(&bcur[i], c) : 0;
    }
    __syncthreads();
    for (int i = threadIdx.x; i < nbk; i += NTH) h[i] = 0;
    __syncthreads();
    for (int e = e0 + threadIdx.x; e < e1; e += NTH) {
        int d = dst[e];
        int b = d >> BKT_SHIFT;
        int p = base[b] + atomicAdd(&h[b], 1);
        pairs[p] = make_int2(src[e], d);
    }
}

// ---------------- fused per-bucket build: count + local scan + row + dinv/invdeg -------
// ---------------- + xs1 prescale + csr fill via LDS cursors. Replaces 5 kernels. -------
// Bucket b exclusively owns nodes [b*256, b*256+256) and csr region [bbase[b], bbase[b+1]).
// row[i] = bbase[b] + exclusive_scan(local counts) -- no global node scan needed.
__global__ __launch_bounds__(NTH) void build_kernel(const int2* __restrict__ pairs,
                                                    const int* __restrict__ bbase,
                                                    int n,
                                                    int* __restrict__ row,
                                                    int* __restrict__ csr,
                                                    float* __restrict__ dinv,
                                                    float* __restrict__ invdeg,
                                                    const float* __restrict__ x,
                                                    float* __restrict__ xs) {
    __shared__ int hc[256];     // counts -> inclusive scan
    __shared__ int hcur[256];   // csr cursors
    const int t = threadIdx.x;
    const int b = blockIdx.x;
    const int p0 = bbase[b], p1 = bbase[b + 1];

    hc[t] = 0;
    __syncthreads();
    for (int p = p0 + t; p < p1; p += NTH)
        atomicAdd(&hc[pairs[p].y & 255], 1);
    __syncthreads();

    const int myc = hc[t];
    // inclusive scan over 256 entries
    for (int off = 1; off < 256; off <<= 1) {
        int v = (t >= off) ? hc[t - off] : 0;
        __syncthreads();
        hc[t] += v;
        __syncthreads();
    }
    const int excl = hc[t] - myc;
    const int r = p0 + excl;
    hcur[t] = r;

    const int gi = b * 256 + t;
    if (gi < n) {
        row[gi] = r;
        float d = (float)myc + 1.0f;
        float di = rsqrtf(d);
        dinv[gi] = di;
        invdeg[gi] = 1.0f / d;
        const float4* xv = reinterpret_cast<const float4*>(x + (size_t)gi * C_IN);
        float4* xsv = reinterpret_cast<float4*>(xs + (size_t)gi * C_IN);
        #pragma unroll
        for (int c4 = 0; c4 < C_IN / 4; ++c4) {
            float4 v = xv[c4];
            v.x *= di; v.y *= di; v.z *= di; v.w *= di;
            xsv[c4] = v;
        }
    }
    __syncthreads();

    for (int p = p0 + t; p < p1; p += NTH) {
        int2 pr = pairs[p];
        int pos = atomicAdd(&hcur[pr.y & 255], 1);
        csr[pos] = pr.x;
    }
}

// ---------------- CSR gather: out[i] = dinv[i]*sum xs[src] + invdeg[i]*self[i] (+b, relu) --
template<int C, bool FINAL>
__global__ __launch_bounds__(NTH) void gather_kernel(const int* __restrict__ row,
                                                     const int* __restrict__ csr,
                                                     const float* __restrict__ xs,
                                                     const float* __restrict__ self,
                                                     const float* __restrict__ dinv,
                                                     const float* __restrict__ invdeg,
                                                     const float* __restrict__ bias,
                                                     float* __restrict__ out, int n) {
    constexpr int G = C / 4;                    // threads per node
    int i = blockIdx.x * (NTH / G) + threadIdx.x / G;
    int q = threadIdx.x % G;
    if (i >= n) return;
    int r0 = row[i], r1 = row[i + 1];
    float4 acc = make_float4(0.f, 0.f, 0.f, 0.f);
    int e = r0;
    for (; e + 7 < r1; e += 8) {
        int s0 = csr[e], s1 = csr[e+1], s2 = csr[e+2], s3 = csr[e+3];
        int s4 = csr[e+4], s5 = csr[e+5], s6 = csr[e+6], s7 = csr[e+7];
        float4 v0 = *reinterpret_cast<const float4*>(xs + (size_t)s0 * C + q * 4);
        float4 v1 = *reinterpret_cast<const float4*>(xs + (size_t)s1 * C + q * 4);
        float4 v2 = *reinterpret_cast<const float4*>(xs + (size_t)s2 * C + q * 4);
        float4 v3 = *reinterpret_cast<const float4*>(xs + (size_t)s3 * C + q * 4);
        float4 v4 = *reinterpret_cast<const float4*>(xs + (size_t)s4 * C + q * 4);
        float4 v5 = *reinterpret_cast<const float4*>(xs + (size_t)s5 * C + q * 4);
        float4 v6 = *reinterpret_cast<const float4*>(xs + (size_t)s6 * C + q * 4);
        float4 v7 = *reinterpret_cast<const float4*>(xs + (size_t)s7 * C + q * 4);
        acc.x += ((v0.x + v1.x) + (v2.x + v3.x)) + ((v4.x + v5.x) + (v6.x + v7.x));
        acc.y += ((v0.y + v1.y) + (v2.y + v3.y)) + ((v4.y + v5.y) + (v6.y + v7.y));
        acc.z += ((v0.z + v1.z) + (v2.z + v3.z)) + ((v4.z + v5.z) + (v6.z + v7.z));
        acc.w += ((v0.w + v1.w) + (v2.w + v3.w)) + ((v4.w + v5.w) + (v6.w + v7.w));
    }
    for (; e + 3 < r1; e += 4) {
        int s0 = csr[e], s1 = csr[e+1], s2 = csr[e+2], s3 = csr[e+3];
        float4 v0 = *reinterpret_cast<const float4*>(xs + (size_t)s0 * C + q * 4);
        float4 v1 = *reinterpret_cast<const float4*>(xs + (size_t)s1 * C + q * 4);
        float4 v2 = *reinterpret_cast<const float4*>(xs + (size_t)s2 * C + q * 4);
        float4 v3 = *reinterpret_cast<const float4*>(xs + (size_t)s3 * C + q * 4);
        acc.x += (v0.x + v1.x) + (v2.x + v3.x);
        acc.y += (v0.y + v1.y) + (v2.y + v3.y);
        acc.z += (v0.z + v1.z) + (v2.z + v3.z);
        acc.w += (v0.w + v1.w) + (v2.w + v3.w);
    }
    for (; e < r1; ++e) {
        int s0 = csr[e];
        float4 v0 = *reinterpret_cast<const float4*>(xs + (size_t)s0 * C + q * 4);
        acc.x += v0.x; acc.y += v0.y; acc.z += v0.z; acc.w += v0.w;
    }
    float di = dinv[i], idg = invdeg[i];
    float4 sv = *reinterpret_cast<const float4*>(self + (size_t)i * C + q * 4);
    float4 o;
    o.x = fmaf(acc.x, di, sv.x * idg);
    o.y = fmaf(acc.y, di, sv.y * idg);
    o.z = fmaf(acc.z, di, sv.z * idg);
    o.w = fmaf(acc.w, di, sv.w * idg);
    if (FINAL) {
        const float4 b = *reinterpret_cast<const float4*>(bias + q * 4);
        o.x = fmaxf(o.x + b.x, 0.f);
        o.y = fmaxf(o.y + b.y, 0.f);
        o.z = fmaxf(o.z + b.z, 0.f);
        o.w = fmaxf(o.w + b.w, 0.f);
    }
    *reinterpret_cast<float4*>(out + (size_t)i * C + q * 4) = o;
}

// ---------------- dense transform: h = [relu](g @ W + b); optional hsc = h * dinv ------
template<int CIN, int COUT, bool BIASRELU, bool WSC>
__global__ __launch_bounds__(NTH) void transform_kernel(const float* __restrict__ g,
                                                        const float* __restrict__ W,
                                                        const float* __restrict__ b,
                                                        const float* __restrict__ dinv,
                                                        float* __restrict__ h,
                                                        float* __restrict__ hsc, int n) {
    __shared__ float Ws[CIN * COUT];
    __shared__ float bs[COUT];
    for (int idx = threadIdx.x; idx < CIN * COUT; idx += NTH) Ws[idx] = W[idx];
    if (BIASRELU && threadIdx.x < COUT) bs[threadIdx.x] = b[threadIdx.x];
    __syncthreads();

    int i = blockIdx.x * NTH + threadIdx.x;
    if (i >= n) return;

    float xr[CIN];
    const float4* xv = reinterpret_cast<const float4*>(g + (size_t)i * CIN);
    #pragma unroll
    for (int k4 = 0; k4 < CIN / 4; ++k4) {
        float4 v = xv[k4];
        xr[k4*4+0] = v.x; xr[k4*4+1] = v.y; xr[k4*4+2] = v.z; xr[k4*4+3] = v.w;
    }

    float di = WSC ? dinv[i] : 0.f;
    float4* hv = reinterpret_cast<float4*>(h + (size_t)i * COUT);
    float4* hscv = WSC ? reinterpret_cast<float4*>(hsc + (size_t)i * COUT) : nullptr;

    #pragma unroll 1
    for (int c4 = 0; c4 < COUT / 4; ++c4) {
        float a0 = 0.f, a1 = 0.f, a2 = 0.f, a3 = 0.f;
        #pragma unroll
        for (int k = 0; k < CIN; ++k) {
            const float4 w = *reinterpret_cast<const float4*>(&Ws[k * COUT + c4 * 4]);
            float xk = xr[k];
            a0 = fmaf(xk, w.x, a0);
            a1 = fmaf(xk, w.y, a1);
            a2 = fmaf(xk, w.z, a2);
            a3 = fmaf(xk, w.w, a3);
        }
        if (BIASRELU) {
            const float4 bv = *reinterpret_cast<const float4*>(&bs[c4 * 4]);
            a0 = fmaxf(a0 + bv.x, 0.f);
            a1 = fmaxf(a1 + bv.y, 0.f);
            a2 = fmaxf(a2 + bv.z, 0.f);
            a3 = fmaxf(a3 + bv.w, 0.f);
        }
        float4 o; o.x = a0; o.y = a1; o.z = a2; o.w = a3;
        hv[c4] = o;
        if (WSC) {
            float4 s; s.x = a0 * di; s.y = a1 * di; s.z = a2 * di; s.w = a3 * di;
            hscv[c4] = s;
        }
    }
}

// ---------------- fused transform2+3: ga2(32) -> relu(·W2+b2)(64) -> ·W3 (32), ×dinv ----
__global__ __launch_bounds__(NTH) void transform23_kernel(const float* __restrict__ g,
                                                          const float* __restrict__ W2,
                                                          const float* __restrict__ b2,
                                                          const float* __restrict__ W3,
                                                          const float* __restrict__ dinv,
                                                          float* __restrict__ t3,
                                                          float* __restrict__ ts3, int n) {
    __shared__ float Ws2[32 * 64];
    __shared__ float Ws3[64 * 32];
    __shared__ float bs2[64];
    for (int idx = threadIdx.x; idx < 2048; idx += NTH) {
        Ws2[idx] = W2[idx];
        Ws3[idx] = W3[idx];
    }
    if (threadIdx.x < 64) bs2[threadIdx.x] = b2[threadIdx.x];
    __syncthreads();

    int i = blockIdx.x * NTH + threadIdx.x;
    if (i >= n) return;

    float xr[32];
    const float4* xv = reinterpret_cast<const float4*>(g + (size_t)i * 32);
    #pragma unroll
    for (int k4 = 0; k4 < 8; ++k4) {
        float4 v = xv[k4];
        xr[k4*4+0] = v.x; xr[k4*4+1] = v.y; xr[k4*4+2] = v.z; xr[k4*4+3] = v.w;
    }

    float hh[64];
    #pragma unroll 1
    for (int c4 = 0; c4 < 16; ++c4) {
        float a0 = 0.f, a1 = 0.f, a2 = 0.f, a3 = 0.f;
        #pragma unroll
        for (int k = 0; k < 32; ++k) {
            const float4 w = *reinterpret_cast<const float4*>(&Ws2[k * 64 + c4 * 4]);
            float xk = xr[k];
            a0 = fmaf(xk, w.x, a0);
            a1 = fmaf(xk, w.y, a1);
            a2 = fmaf(xk, w.z, a2);
            a3 = fmaf(xk, w.w, a3);
        }
        const float4 bv = *reinterpret_cast<const float4*>(&bs2[c4 * 4]);
        hh[c4*4+0] = fmaxf(a0 + bv.x, 0.f);
        hh[c4*4+1] = fmaxf(a1 + bv.y, 0.f);
        hh[c4*4+2] = fmaxf(a2 + bv.z, 0.f);
        hh[c4*4+3] = fmaxf(a3 + bv.w, 0.f);
    }

    float dv = dinv[i];
    float4* t3v = reinterpret_cast<float4*>(t3 + (size_t)i * 32);
    float4* ts3v = reinterpret_cast<float4*>(ts3 + (size_t)i * 32);
    #pragma unroll 1
    for (int c4 = 0; c4 < 8; ++c4) {
        float a0 = 0.f, a1 = 0.f, a2 = 0.f, a3 = 0.f;
        #pragma unroll
        for (int k = 0; k < 64; ++k) {
            const float4 w = *reinterpret_cast<const float4*>(&Ws3[k * 32 + c4 * 4]);
            float hk = hh[k];
            a0 = fmaf(hk, w.x, a0);
            a1 = fmaf(hk, w.y, a1);
            a2 = fmaf(hk, w.z, a2);
            a3 = fmaf(hk, w.w, a3);
        }
        float4 o; o.x = a0; o.y = a1; o.z = a2; o.w = a3;
        t3v[c4] = o;
        float4 s; s.x = a0 * dv; s.y = a1 * dv; s.z = a2 * dv; s.w = a3 * dv;
        ts3v[c4] = s;
    }
}

// ---------------- MLP head via MFMA (layouts m89-verified; bias rides in C) ------------
__global__ __launch_bounds__(NTH, 2) void mlp_mfma_kernel(const float* __restrict__ h3,
                                                          const float* __restrict__ Wf1,
                                                          const float* __restrict__ bf1,
                                                          const float* __restrict__ Wf2,
                                                          float* __restrict__ part, int n) {
    __shared__ unsigned short lds_w[32 * 512];   // 32 KB, [jt][lane][e]
    __shared__ float b1s[512];
    __shared__ float w2s[512];
    const int tid = threadIdx.x;
    const int jh = blockIdx.y;                   // j-half

    for (int idx = tid; idx < 32 * 512; idx += NTH) {
        int k = idx >> 9, jj = idx & 511;        // coalesced over jj
        float wv = Wf1[k * 1024 + jh * 512 + jj];
        int l = ((k >> 3) << 4) | (jj & 15);
        int jt = jj >> 4;
        lds_w[(jt * 64 + l) * 8 + (k & 7)] = f2bf(wv);
    }
    for (int idx = tid; idx < 512; idx += NTH) {
        b1s[idx] = bf1[jh * 512 + idx];
        w2s[idx] = Wf2[jh * 512 + idx];
    }
    __syncthreads();

    const int wid = tid >> 6, lane = tid & 63;
    const int r16 = lane & 15;
    const int kb = (lane >> 4) * 8;
    float* slice = part + (size_t)jh * n;

    #pragma unroll 1
    for (int tt = 0; tt < 8; ++tt) {
        const int i0 = blockIdx.x * 512 + (wid * 8 + tt) * 16;
        const int ia = i0 + r16;

        bf16x8 af;
        if (ia < n) {
            const float4 f0 = *reinterpret_cast<const float4*>(h3 + (size_t)ia * 32 + kb);
            const float4 f1 = *reinterpret_cast<const float4*>(h3 + (size_t)ia * 32 + kb + 4);
            af[0] = (short)f2bf(f0.x); af[1] = (short)f2bf(f0.y);
            af[2] = (short)f2bf(f0.z); af[3] = (short)f2bf(f0.w);
            af[4] = (short)f2bf(f1.x); af[5] = (short)f2bf(f1.y);
            af[6] = (short)f2bf(f1.z); af[7] = (short)f2bf(f1.w);
        } else {
            #pragma unroll
            for (int e = 0; e < 8; ++e) af[e] = 0;
        }

        float p0 = 0.f, p1 = 0.f, p2 = 0.f, p3 = 0.f;
        #pragma unroll 4
        for (int jt = 0; jt < 32; ++jt) {
            const bf16x8 bf = *reinterpret_cast<const bf16x8*>(&lds_w[(jt * 64 + lane) * 8]);
            const float bj = b1s[jt * 16 + r16];
            f32x4 cc; cc[0] = bj; cc[1] = bj; cc[2] = bj; cc[3] = bj;
            f32x4 acc = __builtin_amdgcn_mfma_f32_16x16x32_bf16(af, bf, cc, 0, 0, 0);
            const float gj = w2s[jt * 16 + r16];
            p0 = fmaf(fmaxf(acc[0], 0.f), gj, p0);
            p1 = fmaf(fmaxf(acc[1], 0.f), gj, p1);
            p2 = fmaf(fmaxf(acc[2], 0.f), gj, p2);
            p3 = fmaf(fmaxf(acc[3], 0.f), gj, p3);
        }
        #pragma unroll
        for (int m = 1; m < 16; m <<= 1) {
            p0 += __shfl_xor(p0, m, 64);
            p1 += __shfl_xor(p1, m, 64);
            p2 += __shfl_xor(p2, m, 64);
            p3 += __shfl_xor(p3, m, 64);
        }
        if (r16 == 0) {
            const int rbase = i0 + (lane >> 4) * 4;
            if (rbase + 0 < n) slice[rbase + 0] = p0;
            if (rbase + 1 < n) slice[rbase + 1] = p1;
            if (rbase + 2 < n) slice[rbase + 2] = p2;
            if (rbase + 3 < n) slice[rbase + 3] = p3;
        }
    }
}

__global__ __launch_bounds__(NTH) void sigmoid_kernel(const float* __restrict__ part,
                                                      const float* __restrict__ bf2,
                                                      float* __restrict__ out, int n) {
    int i = blockIdx.x * NTH + threadIdx.x;
    if (i < n) {
        float z = bf2[0] + part[i] + part[(size_t)n + i];
        out[i] = 1.0f / (1.0f + expf(-z));
    }
}

extern "C" void kernel_launch(void* const* d_in, const int* in_sizes, int n_in,
                              void* d_out, int out_size, void* d_ws, size_t ws_size,
                              hipStream_t stream) {
    const float* x    = (const float*)d_in[0];
    const int*   ei   = (const int*)d_in[1];
    const float* W1   = (const float*)d_in[2];
    const float* b1   = (const float*)d_in[3];
    const float* W2   = (const float*)d_in[4];
    const float* b2   = (const float*)d_in[5];
    const float* W3   = (const float*)d_in[6];
    const float* b3   = (const float*)d_in[7];
    const float* Wf1  = (const float*)d_in[8];
    const float* bf1  = (const float*)d_in[9];
    const float* Wf2  = (const float*)d_in[10];
    const float* bf2  = (const float*)d_in[11];
    float* out = (float*)d_out;

    const int n = in_sizes[0] / C_IN;          // 50000
    const int E = in_sizes[1] / 2;             // 800000
    const int* src = ei;
    const int* dst = ei + E;
    const int nbk = (n + 255) >> BKT_SHIFT;    // 196 buckets

    // ---- workspace layout ----
    float* ws = (float*)d_ws;
    float* dinv   = ws;                          // [n]
    float* invdeg = ws + (size_t)n;              // [n]
    float* part   = ws + (size_t)2 * n;          // [2n]
    float* buf1   = ws + (size_t)18 * n;         // [64n]
    float* buf2   = ws + (size_t)82 * n;         // [64n]
    float* buf3   = ws + (size_t)146 * n;        // [32n]
    int*   iw     = (int*)(ws + (size_t)178 * n);
    int*   row    = iw;                          // [n+1]
    int*   csr    = iw + (size_t)n + 1;          // [E]
    int*   bcnt   = iw + (size_t)n + 1 + E;      // [NBK_MAX]
    int*   bbase  = bcnt + NBK_MAX;              // [NBK_MAX+1]
    int*   bcur   = bbase + NBK_MAX + 1;         // [NBK_MAX]
    // pairs aliases buf2: live only between bkt_scatter and build; buf2 (ga1)
    // is first written by gather<16>, which launches after build (stream-ordered).
    int2*  pairs  = (int2*)buf2;                 // [E] = 6.4 MB
    (void)ws_size; (void)n_in; (void)out_size;

    const int nb_n = (n + NTH - 1) / NTH;        // 196

    hipMemsetAsync(bcnt, 0, NBK_MAX * sizeof(int), stream);

    // layer-1 buffers
    float* xs1 = buf1;  // 16n
    float* ga1 = buf2;  // 16n (after pairs dead)
    float* h1  = buf3;  // 32n
    float* xs2 = buf1;  // 32n (after xs1 dead)

    // ---- bucketed CSR build: hist -> scan -> scatter -> fused per-bucket build ----
    bkt_hist_kernel<<<128, NTH, 0, stream>>>(dst, E, nbk, bcnt);
    bkt_scan_kernel<<<1, NTH, 0, stream>>>(bcnt, nbk, bbase, bcur, row, n);
    bkt_scatter_kernel<<<128, NTH, 0, stream>>>(src, dst, E, nbk, bcur, pairs);
    build_kernel<<<nbk, NTH, 0, stream>>>(pairs, bbase, n, row, csr, dinv, invdeg, x, xs1);

    // layer 1: aggregate x (16ch) then transform 16->32
    gather_kernel<16, false><<<(n + 63) / 64, NTH, 0, stream>>>(row, csr, xs1, x, dinv, invdeg, nullptr, ga1, n);
    transform_kernel<16, 32, true, true><<<nb_n, NTH, 0, stream>>>(ga1, W1, b1, dinv, h1, xs2, n);

    // layer 2: aggregate h1 (32ch), then fused transform 32->64->32 (t3 raw, ts3 = t3*dinv)
    float* ga2 = buf2;                   // 32n
    gather_kernel<32, false><<<(n + 31) / 32, NTH, 0, stream>>>(row, csr, xs2, h1, dinv, invdeg, nullptr, ga2, n);
    float* t3  = buf1;                   // 32n (xs2 dead)
    float* ts3 = buf1 + (size_t)32 * n;  // 32n
    transform23_kernel<<<nb_n, NTH, 0, stream>>>(ga2, W2, b2, W3, dinv, t3, ts3, n);

    // layer 3 aggregation (post-transform), fuse b3+relu -> h3
    float* h3 = buf3;                    // 32n (h1 dead)
    gather_kernel<32, true><<<(n + 31) / 32, NTH, 0, stream>>>(row, csr, ts3, t3, dinv, invdeg, b3, h3, n);

    // MLP head: MFMA GEMM + fused relu/fc2/j-reduction -> 2 partials, then sigmoid
    dim3 mgrid((n + 511) / 512, 2);
    mlp_mfma_kernel<<<mgrid, NTH, 0, stream>>>(h3, Wf1, bf1, Wf2, part, n);
    sigmoid_kernel<<<nb_n, NTH, 0, stream>>>(part, bf2, out, n);
}

// Round 12
// 162.956 us; speedup vs baseline: 1.9218x; 1.0386x over previous
//
#include <hip/hip_runtime.h>
#include <math.h>

#define C_IN 16
#define NTH 256
#define BKT_SHIFT 8            // 256 nodes per bucket
#define NBK_MAX 1024

typedef __attribute__((ext_vector_type(8))) short bf16x8;
typedef __attribute__((ext_vector_type(8))) unsigned short u16x8;
typedef __attribute__((ext_vector_type(4))) unsigned short u16x4;
typedef __attribute__((ext_vector_type(4))) float f32x4;

__device__ __forceinline__ unsigned short f2bf(float f) {
    unsigned int u = __float_as_uint(f);
    unsigned int r = (u + 0x7FFFu + ((u >> 16) & 1u)) >> 16;   // RNE
    return (unsigned short)r;
}
__device__ __forceinline__ float bf2f(unsigned short u) {
    return __uint_as_float(((unsigned int)u) << 16);
}

// ---------------- bucket histogram (128 fat blocks, LDS hist, few global atomics) ------
__global__ __launch_bounds__(NTH) void bkt_hist_kernel(const int* __restrict__ dst, int E,
                                                       int nbk, int* __restrict__ bcnt) {
    __shared__ int h[NBK_MAX];
    for (int i = threadIdx.x; i < nbk; i += NTH) h[i] = 0;
    __syncthreads();
    for (int e = blockIdx.x * NTH + threadIdx.x; e < E; e += gridDim.x * NTH)
        atomicAdd(&h[dst[e] >> BKT_SHIFT], 1);
    __syncthreads();
    for (int i = threadIdx.x; i < nbk; i += NTH)
        if (h[i]) atomicAdd(&bcnt[i], h[i]);
}

// ---------------- bucket scan (1 block); also writes row[n] = E ------------------------
__global__ __launch_bounds__(NTH) void bkt_scan_kernel(const int* __restrict__ bcnt, int nbk,
                                                       int* __restrict__ bbase,
                                                       int* __restrict__ bcur,
                                                       int* __restrict__ row, int n) {
    __shared__ int s[NBK_MAX + 1];
    for (int i = threadIdx.x; i < nbk; i += NTH) s[i] = bcnt[i];
    __syncthreads();
    if (threadIdx.x == 0) {
        int acc = 0;
        for (int i = 0; i < nbk; ++i) { int v = s[i]; s[i] = acc; acc += v; }
        s[nbk] = acc;
        row[n] = acc;
    }
    __syncthreads();
    for (int i = threadIdx.x; i <= nbk; i += NTH) bbase[i] = s[i];
    for (int i = threadIdx.x; i < nbk; i += NTH) bcur[i] = s[i];
}

// ---------------- bucket scatter: append (src,dst) into per-bucket regions -------------
__global__ __launch_bounds__(NTH) void bkt_scatter_kernel(const int* __restrict__ src,
                                                          const int* __restrict__ dst, int E,
                                                          int nbk, int* __restrict__ bcur,
                                                          int2* __restrict__ pairs) {
    __shared__ int h[NBK_MAX];
    __shared__ int base[NBK_MAX];
    const int chunk = (E + gridDim.x - 1) / gridDim.x;
    const int e0 = blockIdx.x * chunk;
    const int e1 = min(e0 + chunk, E);

    for (int i = threadIdx.x; i < nbk; i += NTH) h[i] = 0;
    __syncthreads();
    for (int e = e0 + threadIdx.x; e < e1; e += NTH)
        atomicAdd(&h[dst[e] >> BKT_SHIFT], 1);
    __syncthreads();
    for (int i = threadIdx.x; i < nbk; i += NTH) {
        int c = h[i];
        base[i] = c ? atomicAdd(&bcur[i], c) : 0;
    }
    __syncthreads();
    for (int i = threadIdx.x; i < nbk; i += NTH) h[i] = 0;
    __syncthreads();
    for (int e = e0 + threadIdx.x; e < e1; e += NTH) {
        int d = dst[e];
        int b = d >> BKT_SHIFT;
        int p = base[b] + atomicAdd(&h[b], 1);
        pairs[p] = make_int2(src[e], d);
    }
}

// ---------------- fused per-bucket build; xs1 written as bf16 (x * dinv) ---------------
__global__ __launch_bounds__(NTH) void build_kernel(const int2* __restrict__ pairs,
                                                    const int* __restrict__ bbase,
                                                    int n,
                                                    int* __restrict__ row,
                                                    int* __restrict__ csr,
                                                    float* __restrict__ dinv,
                                                    float* __restrict__ invdeg,
                                                    const float* __restrict__ x,
                                                    unsigned short* __restrict__ xs) {
    __shared__ int hc[256];
    __shared__ int hcur[256];
    const int t = threadIdx.x;
    const int b = blockIdx.x;
    const int p0 = bbase[b], p1 = bbase[b + 1];

    hc[t] = 0;
    __syncthreads();
    for (int p = p0 + t; p < p1; p += NTH)
        atomicAdd(&hc[pairs[p].y & 255], 1);
    __syncthreads();

    const int myc = hc[t];
    for (int off = 1; off < 256; off <<= 1) {
        int v = (t >= off) ? hc[t - off] : 0;
        __syncthreads();
        hc[t] += v;
        __syncthreads();
    }
    const int excl = hc[t] - myc;
    const int r = p0 + excl;
    hcur[t] = r;

    const int gi = b * 256 + t;
    if (gi < n) {
        row[gi] = r;
        float d = (float)myc + 1.0f;
        float di = rsqrtf(d);
        dinv[gi] = di;
        invdeg[gi] = 1.0f / d;
        const float4* xv = reinterpret_cast<const float4*>(x + (size_t)gi * C_IN);
        u16x8* xsv = reinterpret_cast<u16x8*>(xs + (size_t)gi * C_IN);
        #pragma unroll
        for (int h8 = 0; h8 < 2; ++h8) {
            float4 v0 = xv[h8 * 2], v1 = xv[h8 * 2 + 1];
            u16x8 w;
            w[0] = f2bf(v0.x * di); w[1] = f2bf(v0.y * di);
            w[2] = f2bf(v0.z * di); w[3] = f2bf(v0.w * di);
            w[4] = f2bf(v1.x * di); w[5] = f2bf(v1.y * di);
            w[6] = f2bf(v1.z * di); w[7] = f2bf(v1.w * di);
            xsv[h8] = w;
        }
    }
    __syncthreads();

    for (int p = p0 + t; p < p1; p += NTH) {
        int2 pr = pairs[p];
        int pos = atomicAdd(&hcur[pr.y & 255], 1);
        csr[pos] = pr.x;
    }
}

// ---------------- bf16-source CSR gather ----------------------------------------------
// out[i] = dinv[i]*sum_bf16(xs[src]) + invdeg[i]*self[i] (+bias, relu if FINAL)
// C channels; G=C/8 threads/node, each owns 8 channels (one 16B u16x8 load per edge).
// FINAL: output bf16 (u16x8) -- identical RNE the MLP applied anyway; else fp32.
template<int C, bool FINAL>
__global__ __launch_bounds__(NTH) void gather_bf_kernel(const int* __restrict__ row,
                                                        const int* __restrict__ csr,
                                                        const unsigned short* __restrict__ xs,
                                                        const float* __restrict__ self,
                                                        const float* __restrict__ dinv,
                                                        const float* __restrict__ invdeg,
                                                        const float* __restrict__ bias,
                                                        void* __restrict__ outp, int n) {
    constexpr int G = C / 8;                    // threads per node
    int i = blockIdx.x * (NTH / G) + threadIdx.x / G;
    int q = threadIdx.x % G;
    if (i >= n) return;
    int r0 = row[i], r1 = row[i + 1];

    float a[8];
    #pragma unroll
    for (int c = 0; c < 8; ++c) a[c] = 0.f;

    int e = r0;
    for (; e + 7 < r1; e += 8) {
        int s[8];
        #pragma unroll
        for (int j = 0; j < 8; ++j) s[j] = csr[e + j];
        u16x8 v[8];
        #pragma unroll
        for (int j = 0; j < 8; ++j)
            v[j] = *reinterpret_cast<const u16x8*>(xs + (size_t)s[j] * C + q * 8);
        #pragma unroll
        for (int j = 0; j < 8; ++j) {
            #pragma unroll
            for (int c = 0; c < 8; ++c) a[c] += bf2f(v[j][c]);
        }
    }
    for (; e < r1; ++e) {
        int s0 = csr[e];
        u16x8 v = *reinterpret_cast<const u16x8*>(xs + (size_t)s0 * C + q * 8);
        #pragma unroll
        for (int c = 0; c < 8; ++c) a[c] += bf2f(v[c]);
    }

    float di = dinv[i], idg = invdeg[i];
    const float4 sv0 = *reinterpret_cast<const float4*>(self + (size_t)i * C + q * 8);
    const float4 sv1 = *reinterpret_cast<const float4*>(self + (size_t)i * C + q * 8 + 4);
    float o[8];
    o[0] = fmaf(a[0], di, sv0.x * idg);
    o[1] = fmaf(a[1], di, sv0.y * idg);
    o[2] = fmaf(a[2], di, sv0.z * idg);
    o[3] = fmaf(a[3], di, sv0.w * idg);
    o[4] = fmaf(a[4], di, sv1.x * idg);
    o[5] = fmaf(a[5], di, sv1.y * idg);
    o[6] = fmaf(a[6], di, sv1.z * idg);
    o[7] = fmaf(a[7], di, sv1.w * idg);

    if (FINAL) {
        const float4 b0 = *reinterpret_cast<const float4*>(bias + q * 8);
        const float4 b1 = *reinterpret_cast<const float4*>(bias + q * 8 + 4);
        o[0] = fmaxf(o[0] + b0.x, 0.f); o[1] = fmaxf(o[1] + b0.y, 0.f);
        o[2] = fmaxf(o[2] + b0.z, 0.f); o[3] = fmaxf(o[3] + b0.w, 0.f);
        o[4] = fmaxf(o[4] + b1.x, 0.f); o[5] = fmaxf(o[5] + b1.y, 0.f);
        o[6] = fmaxf(o[6] + b1.z, 0.f); o[7] = fmaxf(o[7] + b1.w, 0.f);
        u16x8 ob;
        #pragma unroll
        for (int c = 0; c < 8; ++c) ob[c] = f2bf(o[c]);
        *reinterpret_cast<u16x8*>((unsigned short*)outp + (size_t)i * C + q * 8) = ob;
    } else {
        float* outf = (float*)outp;
        float4 w0, w1;
        w0.x = o[0]; w0.y = o[1]; w0.z = o[2]; w0.w = o[3];
        w1.x = o[4]; w1.y = o[5]; w1.z = o[6]; w1.w = o[7];
        *reinterpret_cast<float4*>(outf + (size_t)i * C + q * 8) = w0;
        *reinterpret_cast<float4*>(outf + (size_t)i * C + q * 8 + 4) = w1;
    }
}

// ---------------- transform1: ga1(16) -> relu(·W1+b1)(32) -> h1 fp32 + xs2 bf16*dinv ---
__global__ __launch_bounds__(NTH) void transform1_kernel(const float* __restrict__ g,
                                                         const float* __restrict__ W,
                                                         const float* __restrict__ b,
                                                         const float* __restrict__ dinv,
                                                         float* __restrict__ h,
                                                         unsigned short* __restrict__ hsc,
                                                         int n) {
    __shared__ float Ws[16 * 32];
    __shared__ float bs[32];
    for (int idx = threadIdx.x; idx < 16 * 32; idx += NTH) Ws[idx] = W[idx];
    if (threadIdx.x < 32) bs[threadIdx.x] = b[threadIdx.x];
    __syncthreads();

    int i = blockIdx.x * NTH + threadIdx.x;
    if (i >= n) return;

    float xr[16];
    const float4* xv = reinterpret_cast<const float4*>(g + (size_t)i * 16);
    #pragma unroll
    for (int k4 = 0; k4 < 4; ++k4) {
        float4 v = xv[k4];
        xr[k4*4+0] = v.x; xr[k4*4+1] = v.y; xr[k4*4+2] = v.z; xr[k4*4+3] = v.w;
    }

    float di = dinv[i];
    float4* hv = reinterpret_cast<float4*>(h + (size_t)i * 32);
    u16x4* hscv = reinterpret_cast<u16x4*>(hsc + (size_t)i * 32);

    #pragma unroll 1
    for (int c4 = 0; c4 < 8; ++c4) {
        float a0 = 0.f, a1 = 0.f, a2 = 0.f, a3 = 0.f;
        #pragma unroll
        for (int k = 0; k < 16; ++k) {
            const float4 w = *reinterpret_cast<const float4*>(&Ws[k * 32 + c4 * 4]);
            float xk = xr[k];
            a0 = fmaf(xk, w.x, a0);
            a1 = fmaf(xk, w.y, a1);
            a2 = fmaf(xk, w.z, a2);
            a3 = fmaf(xk, w.w, a3);
        }
        const float4 bv = *reinterpret_cast<const float4*>(&bs[c4 * 4]);
        a0 = fmaxf(a0 + bv.x, 0.f);
        a1 = fmaxf(a1 + bv.y, 0.f);
        a2 = fmaxf(a2 + bv.z, 0.f);
        a3 = fmaxf(a3 + bv.w, 0.f);
        float4 o; o.x = a0; o.y = a1; o.z = a2; o.w = a3;
        hv[c4] = o;
        u16x4 s;
        s[0] = f2bf(a0 * di); s[1] = f2bf(a1 * di);
        s[2] = f2bf(a2 * di); s[3] = f2bf(a3 * di);
        hscv[c4] = s;
    }
}

// ---------------- fused transform2+3: ga2(32)->relu(·W2+b2)(64)->·W3(32); ts3 bf16 -----
__global__ __launch_bounds__(NTH) void transform23_kernel(const float* __restrict__ g,
                                                          const float* __restrict__ W2,
                                                          const float* __restrict__ b2,
                                                          const float* __restrict__ W3,
                                                          const float* __restrict__ dinv,
                                                          float* __restrict__ t3,
                                                          unsigned short* __restrict__ ts3,
                                                          int n) {
    __shared__ float Ws2[32 * 64];
    __shared__ float Ws3[64 * 32];
    __shared__ float bs2[64];
    for (int idx = threadIdx.x; idx < 2048; idx += NTH) {
        Ws2[idx] = W2[idx];
        Ws3[idx] = W3[idx];
    }
    if (threadIdx.x < 64) bs2[threadIdx.x] = b2[threadIdx.x];
    __syncthreads();

    int i = blockIdx.x * NTH + threadIdx.x;
    if (i >= n) return;

    float xr[32];
    const float4* xv = reinterpret_cast<const float4*>(g + (size_t)i * 32);
    #pragma unroll
    for (int k4 = 0; k4 < 8; ++k4) {
        float4 v = xv[k4];
        xr[k4*4+0] = v.x; xr[k4*4+1] = v.y; xr[k4*4+2] = v.z; xr[k4*4+3] = v.w;
    }

    float hh[64];
    #pragma unroll 1
    for (int c4 = 0; c4 < 16; ++c4) {
        float a0 = 0.f, a1 = 0.f, a2 = 0.f, a3 = 0.f;
        #pragma unroll
        for (int k = 0; k < 32; ++k) {
            const float4 w = *reinterpret_cast<const float4*>(&Ws2[k * 64 + c4 * 4]);
            float xk = xr[k];
            a0 = fmaf(xk, w.x, a0);
            a1 = fmaf(xk, w.y, a1);
            a2 = fmaf(xk, w.z, a2);
            a3 = fmaf(xk, w.w, a3);
        }
        const float4 bv = *reinterpret_cast<const float4*>(&bs2[c4 * 4]);
        hh[c4*4+0] = fmaxf(a0 + bv.x, 0.f);
        hh[c4*4+1] = fmaxf(a1 + bv.y, 0.f);
        hh[c4*4+2] = fmaxf(a2 + bv.z, 0.f);
        hh[c4*4+3] = fmaxf(a3 + bv.w, 0.f);
    }

    float dv = dinv[i];
    float4* t3v = reinterpret_cast<float4*>(t3 + (size_t)i * 32);
    u16x4* ts3v = reinterpret_cast<u16x4*>(ts3 + (size_t)i * 32);
    #pragma unroll 1
    for (int c4 = 0; c4 < 8; ++c4) {
        float a0 = 0.f, a1 = 0.f, a2 = 0.f, a3 = 0.f;
        #pragma unroll
        for (int k = 0; k < 64; ++k) {
            const float4 w = *reinterpret_cast<const float4*>(&Ws3[k * 32 + c4 * 4]);
            float hk = hh[k];
            a0 = fmaf(hk, w.x, a0);
            a1 = fmaf(hk, w.y, a1);
            a2 = fmaf(hk, w.z, a2);
            a3 = fmaf(hk, w.w, a3);
        }
        float4 o; o.x = a0; o.y = a1; o.z = a2; o.w = a3;
        t3v[c4] = o;
        u16x4 s;
        s[0] = f2bf(a0 * dv); s[1] = f2bf(a1 * dv);
        s[2] = f2bf(a2 * dv); s[3] = f2bf(a3 * dv);
        ts3v[c4] = s;
    }
}

// ---------------- MLP head via MFMA; h3 already bf16 (layouts m89-verified) ------------
__global__ __launch_bounds__(NTH, 2) void mlp_mfma_kernel(const unsigned short* __restrict__ h3,
                                                          const float* __restrict__ Wf1,
                                                          const float* __restrict__ bf1,
                                                          const float* __restrict__ Wf2,
                                                          float* __restrict__ part, int n) {
    __shared__ unsigned short lds_w[32 * 512];   // 32 KB, [jt][lane][e]
    __shared__ float b1s[512];
    __shared__ float w2s[512];
    const int tid = threadIdx.x;
    const int jh = blockIdx.y;                   // j-half

    for (int idx = tid; idx < 32 * 512; idx += NTH) {
        int k = idx >> 9, jj = idx & 511;        // coalesced over jj
        float wv = Wf1[k * 1024 + jh * 512 + jj];
        int l = ((k >> 3) << 4) | (jj & 15);
        int jt = jj >> 4;
        lds_w[(jt * 64 + l) * 8 + (k & 7)] = f2bf(wv);
    }
    for (int idx = tid; idx < 512; idx += NTH) {
        b1s[idx] = bf1[jh * 512 + idx];
        w2s[idx] = Wf2[jh * 512 + idx];
    }
    __syncthreads();

    const int wid = tid >> 6, lane = tid & 63;
    const int r16 = lane & 15;
    const int kb = (lane >> 4) * 8;
    float* slice = part + (size_t)jh * n;

    #pragma unroll 1
    for (int tt = 0; tt < 8; ++tt) {
        const int i0 = blockIdx.x * 512 + (wid * 8 + tt) * 16;
        const int ia = i0 + r16;

        bf16x8 af;
        if (ia < n) {
            af = *reinterpret_cast<const bf16x8*>(h3 + (size_t)ia * 32 + kb);
        } else {
            #pragma unroll
            for (int e = 0; e < 8; ++e) af[e] = 0;
        }

        float p0 = 0.f, p1 = 0.f, p2 = 0.f, p3 = 0.f;
        #pragma unroll 4
        for (int jt = 0; jt < 32; ++jt) {
            const bf16x8 bf = *reinterpret_cast<const bf16x8*>(&lds_w[(jt * 64 + lane) * 8]);
            const float bj = b1s[jt * 16 + r16];
            f32x4 cc; cc[0] = bj; cc[1] = bj; cc[2] = bj; cc[3] = bj;
            f32x4 acc = __builtin_amdgcn_mfma_f32_16x16x32_bf16(af, bf, cc, 0, 0, 0);
            const float gj = w2s[jt * 16 + r16];
            p0 = fmaf(fmaxf(acc[0], 0.f), gj, p0);
            p1 = fmaf(fmaxf(acc[1], 0.f), gj, p1);
            p2 = fmaf(fmaxf(acc[2], 0.f), gj, p2);
            p3 = fmaf(fmaxf(acc[3], 0.f), gj, p3);
        }
        #pragma unroll
        for (int m = 1; m < 16; m <<= 1) {
            p0 += __shfl_xor(p0, m, 64);
            p1 += __shfl_xor(p1, m, 64);
            p2 += __shfl_xor(p2, m, 64);
            p3 += __shfl_xor(p3, m, 64);
        }
        if (r16 == 0) {
            const int rbase = i0 + (lane >> 4) * 4;
            if (rbase + 0 < n) slice[rbase + 0] = p0;
            if (rbase + 1 < n) slice[rbase + 1] = p1;
            if (rbase + 2 < n) slice[rbase + 2] = p2;
            if (rbase + 3 < n) slice[rbase + 3] = p3;
        }
    }
}

__global__ __launch_bounds__(NTH) void sigmoid_kernel(const float* __restrict__ part,
                                                      const float* __restrict__ bf2,
                                                      float* __restrict__ out, int n) {
    int i = blockIdx.x * NTH + threadIdx.x;
    if (i < n) {
        float z = bf2[0] + part[i] + part[(size_t)n + i];
        out[i] = 1.0f / (1.0f + expf(-z));
    }
}

extern "C" void kernel_launch(void* const* d_in, const int* in_sizes, int n_in,
                              void* d_out, int out_size, void* d_ws, size_t ws_size,
                              hipStream_t stream) {
    const float* x    = (const float*)d_in[0];
    const int*   ei   = (const int*)d_in[1];
    const float* W1   = (const float*)d_in[2];
    const float* b1   = (const float*)d_in[3];
    const float* W2   = (const float*)d_in[4];
    const float* b2   = (const float*)d_in[5];
    const float* W3   = (const float*)d_in[6];
    const float* b3   = (const float*)d_in[7];
    const float* Wf1  = (const float*)d_in[8];
    const float* bf1  = (const float*)d_in[9];
    const float* Wf2  = (const float*)d_in[10];
    const float* bf2  = (const float*)d_in[11];
    float* out = (float*)d_out;

    const int n = in_sizes[0] / C_IN;          // 50000
    const int E = in_sizes[1] / 2;             // 800000
    const int* src = ei;
    const int* dst = ei + E;
    const int nbk = (n + 255) >> BKT_SHIFT;    // 196 buckets

    // ---- workspace layout (float offsets) ----
    float* ws = (float*)d_ws;
    float* dinv   = ws;                          // [n]
    float* invdeg = ws + (size_t)n;              // [n]
    float* part   = ws + (size_t)2 * n;          // [2n]
    float* buf1   = ws + (size_t)18 * n;         // [64n]
    float* buf2   = ws + (size_t)82 * n;         // [64n]
    float* buf3   = ws + (size_t)146 * n;        // [32n]
    int*   iw     = (int*)(ws + (size_t)178 * n);
    int*   row    = iw;                          // [n+1]
    int*   csr    = iw + (size_t)n + 1;          // [E]
    int*   bcnt   = iw + (size_t)n + 1 + E;      // [NBK_MAX]
    int*   bbase  = bcnt + NBK_MAX;              // [NBK_MAX+1]
    int*   bcur   = bbase + NBK_MAX + 1;         // [NBK_MAX]
    int2*  pairs  = (int2*)buf2;                 // [E], dead after build
    (void)ws_size; (void)n_in; (void)out_size;

    const int nb_n = (n + NTH - 1) / NTH;        // 196

    hipMemsetAsync(bcnt, 0, NBK_MAX * sizeof(int), stream);

    // buffer plan (bf16 buffers sized in float-equivalents):
    unsigned short* xs1 = (unsigned short*)buf1;              // 16ch bf16 = 8n fl
    float* ga1 = buf2;                                        // 16n fl (pairs dead)
    float* h1  = buf3;                                        // 32n fl
    unsigned short* xs2 = (unsigned short*)buf1;              // 32ch bf16 = 16n fl (xs1 dead)
    float* ga2 = buf2;                                        // 32n fl
    float* t3  = buf1;                                        // 32n fl (xs2 dead)
    unsigned short* ts3 = (unsigned short*)(buf1 + (size_t)32 * n);  // 16n fl
    unsigned short* h3  = (unsigned short*)buf3;              // 16n fl (h1 dead)

    // ---- bucketed CSR build ----
    bkt_hist_kernel<<<128, NTH, 0, stream>>>(dst, E, nbk, bcnt);
    bkt_scan_kernel<<<1, NTH, 0, stream>>>(bcnt, nbk, bbase, bcur, row, n);
    bkt_scatter_kernel<<<128, NTH, 0, stream>>>(src, dst, E, nbk, bcur, pairs);
    build_kernel<<<nbk, NTH, 0, stream>>>(pairs, bbase, n, row, csr, dinv, invdeg, x, xs1);

    // layer 1: aggregate x (16ch bf16) then transform 16->32 (h1 fp32, xs2 bf16*dinv)
    gather_bf_kernel<16, false><<<(n + 127) / 128, NTH, 0, stream>>>(row, csr, xs1, x, dinv, invdeg, nullptr, ga1, n);
    transform1_kernel<<<nb_n, NTH, 0, stream>>>(ga1, W1, b1, dinv, h1, xs2, n);

    // layer 2: aggregate h1 via xs2 (32ch bf16), fused transform 32->64->32
    gather_bf_kernel<32, false><<<(n + 63) / 64, NTH, 0, stream>>>(row, csr, xs2, h1, dinv, invdeg, nullptr, ga2, n);
    transform23_kernel<<<nb_n, NTH, 0, stream>>>(ga2, W2, b2, W3, dinv, t3, ts3, n);

    // layer 3 aggregation (post-transform), fuse b3+relu, h3 written bf16
    gather_bf_kernel<32, true><<<(n + 63) / 64, NTH, 0, stream>>>(row, csr, ts3, t3, dinv, invdeg, b3, h3, n);

    // MLP head: MFMA GEMM (h3 bf16 direct A-fragments) -> 2 partials, then sigmoid
    dim3 mgrid((n + 511) / 512, 2);
    mlp_mfma_kernel<<<mgrid, NTH, 0, stream>>>(h3, Wf1, bf1, Wf2, part, n);
    sigmoid_kernel<<<nb_n, NTH, 0, stream>>>(part, bf2, out, n);
}